// Round 1
// baseline (1966.004 us; speedup 1.0000x reference)
//
#include <hip/hip_runtime.h>
#include <hip/hip_bf16.h>

#define NNODES 50000
#define NEDGES 400000
#define NEA    450000
#define NG     128
#define DEGCAP 1024

static inline int ceil_div(int a, int b){ return (a + b - 1)/b; }

// ---------------- CSR build ----------------
__global__ void k_deg(const int* __restrict__ dst, int* __restrict__ deg){
  int e = blockIdx.x*blockDim.x + threadIdx.x;
  if (e < NEDGES) atomicAdd(&deg[dst[e]], 1);
}

__global__ void k_scan(const int* __restrict__ deg, int* __restrict__ off){
  __shared__ int s[1024];
  __shared__ int carry_s;
  int t = threadIdx.x;
  if (t==0) carry_s = 0;
  __syncthreads();
  for (int base = 0; base <= NNODES; base += 1024){
    int i = base + t;
    int v = (i < NNODES) ? (deg[i] + 1) : 0;
    s[t] = v; __syncthreads();
    for (int o=1; o<1024; o<<=1){
      int xv = 0;
      if (t >= o) xv = s[t-o];
      __syncthreads();
      s[t] += xv;
      __syncthreads();
    }
    int total = s[1023];
    if (i <= NNODES) off[i] = carry_s + (s[t] - v);
    __syncthreads();
    if (t==0) carry_s += total;
    __syncthreads();
  }
}

__global__ void k_fill(const int* __restrict__ src, const int* __restrict__ dst,
                       const int* __restrict__ off, int* __restrict__ cnt,
                       int* __restrict__ csr_src, int* __restrict__ csr_eid){
  int e = blockIdx.x*blockDim.x + threadIdx.x;
  if (e >= NEDGES) return;
  int d = dst[e];
  int p = off[d] + atomicAdd(&cnt[d], 1);
  csr_src[p] = src[e];
  csr_eid[p] = e;
}

__global__ void k_self(const int* __restrict__ off, int* __restrict__ csr_src, int* __restrict__ csr_eid){
  int n = blockIdx.x*blockDim.x + threadIdx.x;
  if (n >= NNODES) return;
  int p = off[n+1] - 1;
  csr_src[p] = n;
  csr_eid[p] = -1;
}

// ---------------- og (1-gram) ----------------
__global__ void k_og(const float* __restrict__ attr, const int* __restrict__ src,
                     const int* __restrict__ batch, float* __restrict__ og){
  __shared__ float bins[NG*71];
  for (int i = threadIdx.x; i < NG*71; i += blockDim.x) bins[i] = 0.f;
  __syncthreads();
  int stride = gridDim.x * blockDim.x;
  for (int e = blockIdx.x*blockDim.x + threadIdx.x; e < NEDGES; e += stride){
    int b = batch[src[e]];
    const float* row = attr + (size_t)e*72;
    float* bb = bins + b*71;
    for (int k=0; k<71; ++k) atomicAdd(&bb[k], row[k]);
  }
  __syncthreads();
  for (int i = threadIdx.x; i < NG*71; i += blockDim.x)
    if (bins[i] != 0.f) atomicAdd(&og[i], bins[i]);
}

__global__ void k_ognorm(float* __restrict__ og){
  int g = threadIdx.x;
  if (g >= NG) return;
  float s = 0.f;
  for (int k=0;k<71;++k){ float v = og[g*71+k]; s += v*v; }
  float scale = 1.0f / fmaxf(sqrtf(s), 1e-12f);
  for (int k=0;k<71;++k) og[g*71+k] *= scale;
}

// ---------------- f32 tiled GEMM: C[M,Nn] = A[M,K] @ B[K,Nn] ----------------
__global__ __launch_bounds__(256) void k_gemm(const float* __restrict__ A, const float* __restrict__ B,
                                              float* __restrict__ C, int M, int K, int Nn){
  __shared__ float As[16][68];   // [k][m]
  __shared__ float Bs[16][68];   // [k][n]
  int tid = threadIdx.x;
  int tx = tid & 15, ty = tid >> 4;
  int m0 = blockIdx.x * 64, n0 = blockIdx.y * 64;
  float acc[4][4];
  #pragma unroll
  for (int i=0;i<4;++i){ acc[i][0]=0.f; acc[i][1]=0.f; acc[i][2]=0.f; acc[i][3]=0.f; }
  int arow = tid >> 2;
  int acol = (tid & 3) << 2;
  int brow = tid >> 4;
  int bcol = (tid & 15) << 2;
  for (int kt = 0; kt < K; kt += 16){
    float4 av = make_float4(0.f,0.f,0.f,0.f);
    if (m0 + arow < M) av = *(const float4*)(A + (size_t)(m0+arow)*K + kt + acol);
    As[acol+0][arow] = av.x; As[acol+1][arow] = av.y;
    As[acol+2][arow] = av.z; As[acol+3][arow] = av.w;
    float4 bv = *(const float4*)(B + (size_t)(kt+brow)*Nn + n0 + bcol);
    *(float4*)&Bs[brow][bcol] = bv;
    __syncthreads();
    #pragma unroll
    for (int kk=0; kk<16; ++kk){
      float4 a = *(const float4*)&As[kk][ty<<2];
      float4 b = *(const float4*)&Bs[kk][tx<<2];
      acc[0][0]+=a.x*b.x; acc[0][1]+=a.x*b.y; acc[0][2]+=a.x*b.z; acc[0][3]+=a.x*b.w;
      acc[1][0]+=a.y*b.x; acc[1][1]+=a.y*b.y; acc[1][2]+=a.y*b.z; acc[1][3]+=a.y*b.w;
      acc[2][0]+=a.z*b.x; acc[2][1]+=a.z*b.y; acc[2][2]+=a.z*b.z; acc[2][3]+=a.z*b.w;
      acc[3][0]+=a.w*b.x; acc[3][1]+=a.w*b.y; acc[3][2]+=a.w*b.z; acc[3][3]+=a.w*b.w;
    }
    __syncthreads();
  }
  #pragma unroll
  for (int i=0;i<4;++i){
    int m = m0 + (ty<<2) + i;
    if (m < M){
      float4 o = make_float4(acc[i][0],acc[i][1],acc[i][2],acc[i][3]);
      *(float4*)(C + (size_t)m*Nn + n0 + (tx<<2)) = o;
    }
  }
}

// ---------------- attention scalars ----------------
__global__ void k_ve(const float* __restrict__ We, const float* __restrict__ ae,
                     float* __restrict__ ve, int H, int C){
  int t = blockIdx.x*blockDim.x + threadIdx.x;
  if (t >= 72*H) return;
  int k = t / H, h = t - k*H;
  const float* wrow = We + (size_t)k*H*C + (size_t)h*C;
  const float* arow = ae + (size_t)h*C;
  float s = 0.f;
  for (int c=0;c<C;++c) s += wrow[c]*arow[c];
  ve[k*H+h] = s;
}

template<int H>
__global__ void k_se(const float* __restrict__ attr, const float* __restrict__ vef,
                     float* __restrict__ se){
  __shared__ float vel[72*H];
  for (int i = threadIdx.x; i < 72*H; i += blockDim.x) vel[i] = vef[i];
  __syncthreads();
  int e = blockIdx.x*blockDim.x + threadIdx.x;
  if (e >= NEDGES) return;
  const float4* row = (const float4*)(attr + (size_t)e*72);
  float s[H];
  #pragma unroll
  for (int h=0;h<H;++h) s[h]=0.f;
  #pragma unroll
  for (int kk=0; kk<18; ++kk){
    float4 a = row[kk];
    #pragma unroll
    for (int h=0; h<H; ++h)
      s[h] += a.x*vel[(kk*4+0)*H+h] + a.y*vel[(kk*4+1)*H+h]
            + a.z*vel[(kk*4+2)*H+h] + a.w*vel[(kk*4+3)*H+h];
  }
  #pragma unroll
  for (int h=0;h<H;++h) se[(size_t)e*H+h] = s[h];
}

template<int H>
__global__ void k_seloop(const int* __restrict__ off, const int* __restrict__ csr_eid,
                         const float* __restrict__ se, float* __restrict__ seloop){
  int n = blockIdx.x*blockDim.x + threadIdx.x;
  if (n >= NNODES) return;
  int beg = off[n], end = off[n+1];
  int dr = end - 1 - beg;     // real incoming edges (excl self loop)
  float s[H];
  #pragma unroll
  for (int h=0;h<H;++h) s[h]=0.f;
  for (int p=beg; p<beg+dr; ++p){
    int eid = csr_eid[p];
    #pragma unroll
    for (int h=0;h<H;++h) s[h] += se[(size_t)eid*H+h];
  }
  float inv = 1.0f / fmaxf((float)dr, 1.0f);
  #pragma unroll
  for (int h=0;h<H;++h) seloop[(size_t)n*H+h] = s[h]*inv;
}

// per-node src/dst attention scalars, H=4,C=128 (row=512)
__global__ void k_satt512(const float* __restrict__ xs, const float* __restrict__ a_s,
                          const float* __restrict__ a_d,
                          float* __restrict__ ssrc, float* __restrict__ sdst){
  int wid = threadIdx.x >> 6, lane = threadIdx.x & 63;
  int n = blockIdx.x*4 + wid;
  if (n >= NNODES) return;
  const float4* row = (const float4*)(xs + (size_t)n*512);
  float ps = 0.f, pd = 0.f;
  #pragma unroll
  for (int q=0; q<2; ++q){
    int j = lane*2 + q;   // float4 index, lane covers elems 8l..8l+7 (one head)
    float4 v = row[j];
    float4 s4 = ((const float4*)a_s)[j];
    float4 d4 = ((const float4*)a_d)[j];
    ps += v.x*s4.x + v.y*s4.y + v.z*s4.z + v.w*s4.w;
    pd += v.x*d4.x + v.y*d4.y + v.z*d4.z + v.w*d4.w;
  }
  for (int m=8; m>=1; m>>=1){ ps += __shfl_xor(ps,m); pd += __shfl_xor(pd,m); }
  if ((lane & 15) == 0){ ssrc[n*4 + (lane>>4)] = ps; sdst[n*4 + (lane>>4)] = pd; }
}

// H=1, C=64
__global__ void k_satt64(const float* __restrict__ xs, const float* __restrict__ a_s,
                         const float* __restrict__ a_d,
                         float* __restrict__ ssrc, float* __restrict__ sdst){
  int wid = threadIdx.x >> 6, lane = threadIdx.x & 63;
  int n = blockIdx.x*4 + wid;
  if (n >= NNODES) return;
  float v = xs[(size_t)n*64 + lane];
  float ps = v*a_s[lane], pd = v*a_d[lane];
  for (int m=32; m>=1; m>>=1){ ps += __shfl_xor(ps,m); pd += __shfl_xor(pd,m); }
  if (lane==0){ ssrc[n]=ps; sdst[n]=pd; }
}

// ---------------- aggregation: layers 1&2 (H=4,C=128) ----------------
__global__ __launch_bounds__(128) void k_agg12(const float* __restrict__ xs,
    const int* __restrict__ off, const int* __restrict__ csr_src, const int* __restrict__ csr_eid,
    const float* __restrict__ ssrc, const float* __restrict__ sdst,
    const float* __restrict__ se, const float* __restrict__ seloop,
    const float* __restrict__ bias, float* __restrict__ out){
  __shared__ float s_al[DEGCAP][4];
  __shared__ int s_col[DEGCAP];
  int n = blockIdx.x;
  int t = threadIdx.x;
  int beg = off[n];
  int deg = off[n+1] - beg;
  if (deg > DEGCAP) deg = DEGCAP;   // structurally impossible for this dataset
  for (int base=0; base<deg; base+=32){
    int e = base + (t>>2);
    int h = t & 3;
    if (e < deg){
      int col = csr_src[beg+e];
      int eid = csr_eid[beg+e];
      float s = ssrc[col*4+h] + sdst[n*4+h] + (eid < 0 ? seloop[n*4+h] : se[(size_t)eid*4+h]);
      s = (s > 0.f) ? s : 0.2f*s;   // leaky_relu 0.2
      s_al[e][h] = s;
      if (h==0) s_col[e] = col;
    }
  }
  __syncthreads();
  if (t < 4){
    float m = -1e30f;
    for (int e=0;e<deg;++e) m = fmaxf(m, s_al[e][t]);
    float z = 0.f;
    for (int e=0;e<deg;++e){ float ex = expf(s_al[e][t]-m); s_al[e][t] = ex; z += ex; }
    float inv = 1.0f/(z + 1e-16f);
    for (int e=0;e<deg;++e) s_al[e][t] *= inv;
  }
  __syncthreads();
  float4 acc = make_float4(0.f,0.f,0.f,0.f);
  int hh = t >> 5;   // head of channels 4t..4t+3
  for (int e=0; e<deg; ++e){
    float a = s_al[e][hh];
    float4 v = ((const float4*)(xs + (size_t)s_col[e]*512))[t];
    acc.x += a*v.x; acc.y += a*v.y; acc.z += a*v.z; acc.w += a*v.w;
  }
  float4 b4 = ((const float4*)bias)[t];
  float4 o;
  o.x = fmaxf(acc.x + b4.x, 0.f);
  o.y = fmaxf(acc.y + b4.y, 0.f);
  o.z = fmaxf(acc.z + b4.z, 0.f);
  o.w = fmaxf(acc.w + b4.w, 0.f);
  ((float4*)(out + (size_t)n*512))[t] = o;
}

// ---------------- aggregation: layer 3 (H=1,C=64) ----------------
__global__ __launch_bounds__(64) void k_agg3(const float* __restrict__ xs,
    const int* __restrict__ off, const int* __restrict__ csr_src, const int* __restrict__ csr_eid,
    const float* __restrict__ ssrc, const float* __restrict__ sdst,
    const float* __restrict__ se, const float* __restrict__ seloop,
    const float* __restrict__ bias, float* __restrict__ out){
  __shared__ float s_al[DEGCAP];
  __shared__ int s_col[DEGCAP];
  int n = blockIdx.x;
  int t = threadIdx.x;
  int beg = off[n];
  int deg = off[n+1] - beg;
  if (deg > DEGCAP) deg = DEGCAP;
  for (int base=0; base<deg; base+=64){
    int e = base + t;
    if (e < deg){
      int col = csr_src[beg+e];
      int eid = csr_eid[beg+e];
      float s = ssrc[col] + sdst[n] + (eid < 0 ? seloop[n] : se[eid]);
      s = (s > 0.f) ? s : 0.2f*s;
      s_al[e] = s;
      s_col[e] = col;
    }
  }
  __syncthreads();
  if (t == 0){
    float m = -1e30f;
    for (int e=0;e<deg;++e) m = fmaxf(m, s_al[e]);
    float z = 0.f;
    for (int e=0;e<deg;++e){ float ex = expf(s_al[e]-m); s_al[e] = ex; z += ex; }
    float inv = 1.0f/(z + 1e-16f);
    for (int e=0;e<deg;++e) s_al[e] *= inv;
  }
  __syncthreads();
  float acc = 0.f;
  for (int e=0; e<deg; ++e) acc += s_al[e] * xs[(size_t)s_col[e]*64 + t];
  out[(size_t)n*64 + t] = fmaxf(acc + bias[t], 0.f);
}

// ---------------- pooling (batch is sorted) ----------------
__global__ __launch_bounds__(64) void k_pool(const float* __restrict__ h, const int* __restrict__ batch,
                                             float* __restrict__ pooled, int* __restrict__ cntg){
  int l = threadIdx.x;
  int start = blockIdx.x * 256;
  if (start >= NNODES) return;
  int endn = min(start + 256, NNODES);
  float acc = 0.f;
  int curg = batch[start];
  int run = 0;
  for (int n = start; n < endn; ++n){
    int g = batch[n];
    if (g != curg){
      atomicAdd(&pooled[curg*64+l], acc);
      if (l==0) atomicAdd(&cntg[curg], run);
      acc = 0.f; run = 0; curg = g;
    }
    acc += h[(size_t)n*64 + l];
    ++run;
  }
  atomicAdd(&pooled[curg*64+l], acc);
  if (l==0) atomicAdd(&cntg[curg], run);
}

// ---------------- final FFN + softmax ----------------
__global__ void k_ffn(const float* __restrict__ pooled, const int* __restrict__ cntg,
                      const float* __restrict__ og,
                      const float* __restrict__ Wf1, const float* __restrict__ bf1,
                      const float* __restrict__ Wf2, const float* __restrict__ bf2,
                      float* __restrict__ out){
  __shared__ float z[135];
  __shared__ float z1[67];
  __shared__ float o2[2];
  int g = blockIdx.x, t = threadIdx.x;
  if (t < 64) z[t] = pooled[g*64+t] * (1.0f/fmaxf((float)cntg[g], 1.0f));
  else if (t < 135) z[t] = og[g*71 + (t-64)];
  __syncthreads();
  if (t < 67){
    float s = bf1[t];
    for (int d=0; d<135; ++d) s += z[d]*Wf1[d*67+t];
    z1[t] = fmaxf(s, 0.f);
  }
  __syncthreads();
  if (t < 2){
    float s = bf2[t];
    for (int j=0; j<67; ++j) s += z1[j]*Wf2[j*2+t];
    o2[t] = s;
  }
  __syncthreads();
  if (t == 0){
    float m = fmaxf(o2[0], o2[1]);
    float e0 = expf(o2[0]-m), e1 = expf(o2[1]-m);
    float inv = 1.0f/(e0+e1);
    out[g*2+0] = e0*inv;
    out[g*2+1] = e1*inv;
  }
}

extern "C" void kernel_launch(void* const* d_in, const int* in_sizes, int n_in,
                              void* d_out, int out_size, void* d_ws, size_t ws_size,
                              hipStream_t stream){
  const float* x     = (const float*)d_in[0];
  const int*   ei    = (const int*)d_in[1];
  const float* eattr = (const float*)d_in[2];
  const int*   batch = (const int*)d_in[3];
  const float* W1  = (const float*)d_in[4];
  const float* We1 = (const float*)d_in[5];
  const float* as1 = (const float*)d_in[6];
  const float* ad1 = (const float*)d_in[7];
  const float* ae1 = (const float*)d_in[8];
  const float* b1  = (const float*)d_in[9];
  const float* W2  = (const float*)d_in[10];
  const float* We2 = (const float*)d_in[11];
  const float* as2 = (const float*)d_in[12];
  const float* ad2 = (const float*)d_in[13];
  const float* ae2 = (const float*)d_in[14];
  const float* b2  = (const float*)d_in[15];
  const float* W3  = (const float*)d_in[16];
  const float* We3 = (const float*)d_in[17];
  const float* as3 = (const float*)d_in[18];
  const float* ad3 = (const float*)d_in[19];
  const float* ae3 = (const float*)d_in[20];
  const float* b3  = (const float*)d_in[21];
  const float* Wf1 = (const float*)d_in[22];
  const float* bf1 = (const float*)d_in[23];
  const float* Wf2 = (const float*)d_in[24];
  const float* bf2 = (const float*)d_in[25];
  (void)in_sizes; (void)n_in; (void)out_size; (void)ws_size;
  const int* src = ei;
  const int* dst = ei + NEDGES;
  float* out = (float*)d_out;

  char* base = (char*)d_ws;
  size_t woff = 0;
  auto alloc = [&](size_t bytes)->char*{
    char* p = base + woff;
    woff += (bytes + 255) & ~(size_t)255;
    return p;
  };
  float* bufA   = (float*)alloc((size_t)NNODES*512*4);
  float* bufB   = (float*)alloc((size_t)NNODES*512*4);
  float* se     = (float*)alloc((size_t)NEDGES*4*4);
  float* seloop = (float*)alloc((size_t)NNODES*4*4);
  float* ssrc   = (float*)alloc((size_t)NNODES*4*4);
  float* sdst   = (float*)alloc((size_t)NNODES*4*4);
  float* ve     = (float*)alloc(72*4*4);
  int*   deg    = (int*)alloc((size_t)NNODES*4);
  int*   cnt    = (int*)alloc((size_t)NNODES*4);
  int*   csroff = (int*)alloc((size_t)(NNODES+1)*4);
  int*   csrsrc = (int*)alloc((size_t)NEA*4);
  int*   csreid = (int*)alloc((size_t)NEA*4);
  float* og     = (float*)alloc((size_t)NG*71*4);
  float* pooled = (float*)alloc((size_t)NG*64*4);
  int*   cntg   = (int*)alloc((size_t)NG*4);
  float* xs3 = bufA;                       // reuse: xs2 dead by then
  float* h3  = bufA + (size_t)NNODES*64;   // disjoint region of bufA

  hipMemsetAsync(deg,    0, (size_t)NNODES*4, stream);
  hipMemsetAsync(cnt,    0, (size_t)NNODES*4, stream);
  hipMemsetAsync(og,     0, (size_t)NG*71*4, stream);
  hipMemsetAsync(pooled, 0, (size_t)NG*64*4, stream);
  hipMemsetAsync(cntg,   0, (size_t)NG*4, stream);

  // CSR build (dst-grouped, self loop in last slot of each segment)
  k_deg <<<ceil_div(NEDGES,256),256,0,stream>>>(dst, deg);
  k_scan<<<1,1024,0,stream>>>(deg, csroff);
  k_fill<<<ceil_div(NEDGES,256),256,0,stream>>>(src, dst, csroff, cnt, csrsrc, csreid);
  k_self<<<ceil_div(NNODES,256),256,0,stream>>>(csroff, csrsrc, csreid);

  // 1-gram feature
  k_og    <<<64,256,0,stream>>>(eattr, src, batch, og);
  k_ognorm<<<1,128,0,stream>>>(og);

  dim3 g512(ceil_div(NNODES,64), 8);
  dim3 g64 (ceil_div(NNODES,64), 1);

  // ---- layer 1 ----
  k_gemm<<<g512,256,0,stream>>>(x, W1, bufA, NNODES, 64, 512);
  k_ve  <<<2,256,0,stream>>>(We1, ae1, ve, 4, 128);
  k_se<4>    <<<ceil_div(NEDGES,256),256,0,stream>>>(eattr, ve, se);
  k_seloop<4><<<ceil_div(NNODES,256),256,0,stream>>>(csroff, csreid, se, seloop);
  k_satt512  <<<ceil_div(NNODES,4),256,0,stream>>>(bufA, as1, ad1, ssrc, sdst);
  k_agg12    <<<NNODES,128,0,stream>>>(bufA, csroff, csrsrc, csreid, ssrc, sdst, se, seloop, b1, bufB);

  // ---- layer 2 ----
  k_gemm<<<g512,256,0,stream>>>(bufB, W2, bufA, NNODES, 512, 512);
  k_ve  <<<2,256,0,stream>>>(We2, ae2, ve, 4, 128);
  k_se<4>    <<<ceil_div(NEDGES,256),256,0,stream>>>(eattr, ve, se);
  k_seloop<4><<<ceil_div(NNODES,256),256,0,stream>>>(csroff, csreid, se, seloop);
  k_satt512  <<<ceil_div(NNODES,4),256,0,stream>>>(bufA, as2, ad2, ssrc, sdst);
  k_agg12    <<<NNODES,128,0,stream>>>(bufA, csroff, csrsrc, csreid, ssrc, sdst, se, seloop, b2, bufB);

  // ---- layer 3 (H=1, C=64) ----
  k_gemm<<<g64,256,0,stream>>>(bufB, W3, xs3, NNODES, 512, 64);
  k_ve  <<<1,128,0,stream>>>(We3, ae3, ve, 1, 64);
  k_se<1>    <<<ceil_div(NEDGES,256),256,0,stream>>>(eattr, ve, se);
  k_seloop<1><<<ceil_div(NNODES,256),256,0,stream>>>(csroff, csreid, se, seloop);
  k_satt64   <<<ceil_div(NNODES,4),256,0,stream>>>(xs3, as3, ad3, ssrc, sdst);
  k_agg3     <<<NNODES,64,0,stream>>>(xs3, csroff, csrsrc, csreid, ssrc, sdst, se, seloop, b3, h3);

  // ---- pool + FFN + softmax ----
  k_pool<<<ceil_div(NNODES,256),64,0,stream>>>(h3, batch, pooled, cntg);
  k_ffn <<<NG,192,0,stream>>>(pooled, cntg, og, Wf1, bf1, Wf2, bf2, out);
}

// Round 2
// 1363.004 us; speedup vs baseline: 1.4424x; 1.4424x over previous
//
#include <hip/hip_runtime.h>

#define NNODES 50000
#define NEDGES 400000
#define NEA    450000
#define NG     128
#define DEGCAP 1024
#define OGW    72   // padded og row stride (71 used)

typedef unsigned short u16;
typedef unsigned int   u32;
typedef __attribute__((ext_vector_type(8))) short short8v;
typedef __attribute__((ext_vector_type(4))) float f32x4;

static inline int ceil_div(int a, int b){ return (a + b - 1)/b; }

__device__ __forceinline__ u16 f2bf(float f){
  u32 u = __builtin_bit_cast(u32, f);
  u = (u + 0x7fffu + ((u >> 16) & 1u)) >> 16;   // RNE
  return (u16)u;
}

// ---------------- casts ----------------
__global__ void k_cast4(const float* __restrict__ in, u16* __restrict__ outb, int n4){
  int i = blockIdx.x*blockDim.x + threadIdx.x;
  if (i >= n4) return;
  float4 v = ((const float4*)in)[i];
  ((ushort4*)outb)[i] = make_ushort4(f2bf(v.x), f2bf(v.y), f2bf(v.z), f2bf(v.w));
}

// W [K,N] f32 -> Wt [N,K] bf16 (transposed for coalesced B staging)
__global__ void k_castWt(const float* __restrict__ W, u16* __restrict__ Wt, int K, int Nn){
  int idx = blockIdx.x*blockDim.x + threadIdx.x;
  if (idx >= K*Nn) return;
  int n = idx / K, k = idx - n*K;
  Wt[idx] = f2bf(W[(size_t)k*Nn + n]);
}

// ---------------- CSR build ----------------
__global__ void k_deg(const int* __restrict__ dst, int* __restrict__ deg){
  int e = blockIdx.x*blockDim.x + threadIdx.x;
  if (e < NEDGES) atomicAdd(&deg[dst[e]], 1);
}

__global__ __launch_bounds__(1024) void k_scan(const int* __restrict__ deg, int* __restrict__ off){
  __shared__ int s[1024];
  const int CH = (NNODES + 1023)/1024;   // 49
  int t = threadIdx.x;
  int i0 = t*CH, i1 = min(i0 + CH, NNODES);
  int loc = 0;
  for (int i = i0; i < i1; ++i) loc += deg[i] + 1;
  s[t] = loc; __syncthreads();
  for (int o = 1; o < 1024; o <<= 1){
    int v = (t >= o) ? s[t-o] : 0;
    __syncthreads();
    s[t] += v;
    __syncthreads();
  }
  int excl = s[t] - loc;
  for (int i = i0; i < i1; ++i){ off[i] = excl; excl += deg[i] + 1; }
  if (t == 1023) off[NNODES] = s[1023];
}

__global__ void k_fill(const int* __restrict__ src, const int* __restrict__ dst,
                       const int* __restrict__ off, int* __restrict__ cnt,
                       int* __restrict__ csr_src, int* __restrict__ csr_eid){
  int e = blockIdx.x*blockDim.x + threadIdx.x;
  if (e >= NEDGES) return;
  int d = dst[e];
  int p = off[d] + atomicAdd(&cnt[d], 1);
  csr_src[p] = src[e];
  csr_eid[p] = e;
}

__global__ void k_self(const int* __restrict__ off, int* __restrict__ csr_src, int* __restrict__ csr_eid){
  int n = blockIdx.x*blockDim.x + threadIdx.x;
  if (n >= NNODES) return;
  int p = off[n+1] - 1;
  csr_src[p] = n;
  csr_eid[p] = -1;
}

// ---------------- og (1-gram): wave-per-edge, lane-per-column ----------------
__global__ __launch_bounds__(512) void k_og(const float* __restrict__ attr, const int* __restrict__ src,
                     const int* __restrict__ batch, float* __restrict__ partials){
  __shared__ float bins[NG*OGW];
  int t = threadIdx.x;
  for (int i = t; i < NG*OGW; i += 512) bins[i] = 0.f;
  __syncthreads();
  int lane = t & 63, w = t >> 6;
  const int EPB = (NEDGES + gridDim.x - 1)/gridDim.x;
  int e0 = blockIdx.x*EPB, e1 = min(e0 + EPB, NEDGES);
  for (int e = e0 + w; e < e1; e += 8){
    int bg = batch[src[e]];
    float v0 = attr[(size_t)e*72 + lane];
    atomicAdd(&bins[bg*OGW + lane], v0);
    if (lane < 7){
      float v1 = attr[(size_t)e*72 + 64 + lane];
      atomicAdd(&bins[bg*OGW + 64 + lane], v1);
    }
  }
  __syncthreads();
  for (int i = t; i < NG*OGW; i += 512)
    partials[(size_t)blockIdx.x*NG*OGW + i] = bins[i];
}

__global__ void k_ogreduce(const float* __restrict__ partials, float* __restrict__ og, int nb){
  int i = blockIdx.x*blockDim.x + threadIdx.x;
  if (i >= NG*OGW) return;
  float s = 0.f;
  for (int b = 0; b < nb; ++b) s += partials[(size_t)b*NG*OGW + i];
  og[i] = s;
}

__global__ void k_ognorm(float* __restrict__ og){
  int g = threadIdx.x;
  if (g >= NG) return;
  float s = 0.f;
  for (int k = 0; k < 71; ++k){ float v = og[g*OGW+k]; s += v*v; }
  float scale = 1.0f / fmaxf(sqrtf(s), 1e-12f);
  for (int k = 0; k < 71; ++k) og[g*OGW+k] *= scale;
}

// ---------------- bf16 MFMA GEMM: C[M,Nn] = A[M,K] @ Bt[Nn,K]^T ----------------
// A bf16 row-major [M,K]; Bt bf16 row-major [Nn,K]; C f32 [M,Nn].
// Tile: BM=128, BN=64, BK=32. 4 waves; wave w owns rows w*32..w*32+31 (2x4 frags of 16x16).
__global__ __launch_bounds__(256) void k_gemm_bf16(const u16* __restrict__ A,
    const u16* __restrict__ Bt, float* __restrict__ C, int M, int K, int Nn){
  __shared__ __align__(16) u16 As[128*32];
  __shared__ __align__(16) u16 Bs[64*32];
  const int tid = threadIdx.x;
  const int wid = tid >> 6, lane = tid & 63;
  const int l15 = lane & 15, kslot = lane >> 4;
  const int m0 = blockIdx.x * 128, n0 = blockIdx.y * 64;
  f32x4 acc[2][4];
  #pragma unroll
  for (int mi = 0; mi < 2; ++mi)
    #pragma unroll
    for (int ni = 0; ni < 4; ++ni)
      acc[mi][ni] = (f32x4){0.f,0.f,0.f,0.f};

  for (int kt = 0; kt < K; kt += 32){
    // stage A: 128 rows x 32 k (8 KB) = 512 chunks of 16B; XOR-swizzled
    #pragma unroll
    for (int i = 0; i < 2; ++i){
      int chunk = tid + i*256;
      int row = chunk >> 2, c16 = chunk & 3;
      uint4 v = make_uint4(0u,0u,0u,0u);
      int grow = m0 + row;
      if (grow < M) v = *(const uint4*)(A + (size_t)grow*K + kt + c16*8);
      *(uint4*)(&As[row*32 + ((c16*8) ^ ((row&3)<<3))]) = v;
    }
    // stage B^T: 64 cols x 32 k (4 KB) = 256 chunks
    {
      int row = tid >> 2, c16 = tid & 3;
      uint4 v = *(const uint4*)(Bt + (size_t)(n0+row)*K + kt + c16*8);
      *(uint4*)(&Bs[row*32 + ((c16*8) ^ ((row&3)<<3))]) = v;
    }
    __syncthreads();
    short8v a[2], b[4];
    #pragma unroll
    for (int mi = 0; mi < 2; ++mi){
      int r = wid*32 + mi*16 + l15;
      a[mi] = *(const short8v*)(&As[r*32 + ((kslot*8) ^ ((r&3)<<3))]);
    }
    #pragma unroll
    for (int ni = 0; ni < 4; ++ni){
      int c = ni*16 + l15;
      b[ni] = *(const short8v*)(&Bs[c*32 + ((kslot*8) ^ ((c&3)<<3))]);
    }
    #pragma unroll
    for (int mi = 0; mi < 2; ++mi)
      #pragma unroll
      for (int ni = 0; ni < 4; ++ni)
        acc[mi][ni] = __builtin_amdgcn_mfma_f32_16x16x32_bf16(a[mi], b[ni], acc[mi][ni], 0, 0, 0);
    __syncthreads();
  }
  #pragma unroll
  for (int mi = 0; mi < 2; ++mi){
    #pragma unroll
    for (int ni = 0; ni < 4; ++ni){
      #pragma unroll
      for (int r = 0; r < 4; ++r){
        int grow = m0 + wid*32 + mi*16 + kslot*4 + r;   // row=(lane>>4)*4+reg (m89/m91)
        if (grow < M) C[(size_t)grow*Nn + n0 + ni*16 + l15] = acc[mi][ni][r];
      }
    }
  }
}

// ---------------- attention scalars ----------------
__global__ void k_ve(const float* __restrict__ We, const float* __restrict__ ae,
                     float* __restrict__ ve, int H, int C){
  int t = blockIdx.x*blockDim.x + threadIdx.x;
  if (t >= 72*H) return;
  int k = t / H, h = t - k*H;
  const float* wrow = We + (size_t)k*H*C + (size_t)h*C;
  const float* arow = ae + (size_t)h*C;
  float s = 0.f;
  for (int c = 0; c < C; ++c) s += wrow[c]*arow[c];
  ve[k*H+h] = s;
}

template<int H>
__global__ void k_se(const float* __restrict__ attr, const float* __restrict__ vef,
                     float* __restrict__ se){
  __shared__ float vel[72*H];
  for (int i = threadIdx.x; i < 72*H; i += blockDim.x) vel[i] = vef[i];
  __syncthreads();
  int e = blockIdx.x*blockDim.x + threadIdx.x;
  if (e >= NEDGES) return;
  const float4* row = (const float4*)(attr + (size_t)e*72);
  float s[H];
  #pragma unroll
  for (int h = 0; h < H; ++h) s[h] = 0.f;
  #pragma unroll
  for (int kk = 0; kk < 18; ++kk){
    float4 a = row[kk];
    #pragma unroll
    for (int h = 0; h < H; ++h)
      s[h] += a.x*vel[(kk*4+0)*H+h] + a.y*vel[(kk*4+1)*H+h]
            + a.z*vel[(kk*4+2)*H+h] + a.w*vel[(kk*4+3)*H+h];
  }
  #pragma unroll
  for (int h = 0; h < H; ++h) se[(size_t)e*H+h] = s[h];
}

template<int H>
__global__ void k_seloop(const int* __restrict__ off, const int* __restrict__ csr_eid,
                         const float* __restrict__ se, float* __restrict__ seloop){
  int n = blockIdx.x*blockDim.x + threadIdx.x;
  if (n >= NNODES) return;
  int beg = off[n], end = off[n+1];
  int dr = end - 1 - beg;
  float s[H];
  #pragma unroll
  for (int h = 0; h < H; ++h) s[h] = 0.f;
  for (int p = beg; p < beg+dr; ++p){
    int eid = csr_eid[p];
    #pragma unroll
    for (int h = 0; h < H; ++h) s[h] += se[(size_t)eid*H+h];
  }
  float inv = 1.0f / fmaxf((float)dr, 1.0f);
  #pragma unroll
  for (int h = 0; h < H; ++h) seloop[(size_t)n*H+h] = s[h]*inv;
}

__global__ void k_satt512(const float* __restrict__ xs, const float* __restrict__ a_s,
                          const float* __restrict__ a_d,
                          float* __restrict__ ssrc, float* __restrict__ sdst){
  int wid = threadIdx.x >> 6, lane = threadIdx.x & 63;
  int n = blockIdx.x*4 + wid;
  if (n >= NNODES) return;
  const float4* row = (const float4*)(xs + (size_t)n*512);
  float ps = 0.f, pd = 0.f;
  #pragma unroll
  for (int q = 0; q < 2; ++q){
    int j = lane*2 + q;
    float4 v = row[j];
    float4 s4 = ((const float4*)a_s)[j];
    float4 d4 = ((const float4*)a_d)[j];
    ps += v.x*s4.x + v.y*s4.y + v.z*s4.z + v.w*s4.w;
    pd += v.x*d4.x + v.y*d4.y + v.z*d4.z + v.w*d4.w;
  }
  for (int m = 8; m >= 1; m >>= 1){ ps += __shfl_xor(ps,m); pd += __shfl_xor(pd,m); }
  if ((lane & 15) == 0){ ssrc[n*4 + (lane>>4)] = ps; sdst[n*4 + (lane>>4)] = pd; }
}

__global__ void k_satt64(const float* __restrict__ xs, const float* __restrict__ a_s,
                         const float* __restrict__ a_d,
                         float* __restrict__ ssrc, float* __restrict__ sdst){
  int wid = threadIdx.x >> 6, lane = threadIdx.x & 63;
  int n = blockIdx.x*4 + wid;
  if (n >= NNODES) return;
  float v = xs[(size_t)n*64 + lane];
  float ps = v*a_s[lane], pd = v*a_d[lane];
  for (int m = 32; m >= 1; m >>= 1){ ps += __shfl_xor(ps,m); pd += __shfl_xor(pd,m); }
  if (lane == 0){ ssrc[n] = ps; sdst[n] = pd; }
}

// ---------------- aggregation: layers 1&2 (H=4,C=128), bf16 output ----------------
__global__ __launch_bounds__(128) void k_agg12(const float* __restrict__ xs,
    const int* __restrict__ off, const int* __restrict__ csr_src, const int* __restrict__ csr_eid,
    const float* __restrict__ ssrc, const float* __restrict__ sdst,
    const float* __restrict__ se, const float* __restrict__ seloop,
    const float* __restrict__ bias, u16* __restrict__ out){
  __shared__ float s_al[DEGCAP][4];
  __shared__ int s_col[DEGCAP];
  int n = blockIdx.x;
  int t = threadIdx.x;
  int beg = off[n];
  int deg = off[n+1] - beg;
  if (deg > DEGCAP) deg = DEGCAP;
  for (int base = 0; base < deg; base += 32){
    int e = base + (t>>2);
    int h = t & 3;
    if (e < deg){
      int col = csr_src[beg+e];
      int eid = csr_eid[beg+e];
      float s = ssrc[col*4+h] + sdst[n*4+h] + (eid < 0 ? seloop[n*4+h] : se[(size_t)eid*4+h]);
      s = (s > 0.f) ? s : 0.2f*s;
      s_al[e][h] = s;
      if (h == 0) s_col[e] = col;
    }
  }
  __syncthreads();
  if (t < 4){
    float m = -1e30f;
    for (int e = 0; e < deg; ++e) m = fmaxf(m, s_al[e][t]);
    float z = 0.f;
    for (int e = 0; e < deg; ++e){ float ex = expf(s_al[e][t]-m); s_al[e][t] = ex; z += ex; }
    float inv = 1.0f/(z + 1e-16f);
    for (int e = 0; e < deg; ++e) s_al[e][t] *= inv;
  }
  __syncthreads();
  float4 acc = make_float4(0.f,0.f,0.f,0.f);
  int hh = t >> 5;
  for (int e = 0; e < deg; ++e){
    float a = s_al[e][hh];
    float4 v = ((const float4*)(xs + (size_t)s_col[e]*512))[t];
    acc.x += a*v.x; acc.y += a*v.y; acc.z += a*v.z; acc.w += a*v.w;
  }
  float4 b4 = ((const float4*)bias)[t];
  float ox = fmaxf(acc.x + b4.x, 0.f);
  float oy = fmaxf(acc.y + b4.y, 0.f);
  float oz = fmaxf(acc.z + b4.z, 0.f);
  float ow = fmaxf(acc.w + b4.w, 0.f);
  ((ushort4*)(out + (size_t)n*512))[t] = make_ushort4(f2bf(ox), f2bf(oy), f2bf(oz), f2bf(ow));
}

// ---------------- aggregation: layer 3 (H=1,C=64), f32 output ----------------
__global__ __launch_bounds__(64) void k_agg3(const float* __restrict__ xs,
    const int* __restrict__ off, const int* __restrict__ csr_src, const int* __restrict__ csr_eid,
    const float* __restrict__ ssrc, const float* __restrict__ sdst,
    const float* __restrict__ se, const float* __restrict__ seloop,
    const float* __restrict__ bias, float* __restrict__ out){
  __shared__ float s_al[DEGCAP];
  __shared__ int s_col[DEGCAP];
  int n = blockIdx.x;
  int t = threadIdx.x;
  int beg = off[n];
  int deg = off[n+1] - beg;
  if (deg > DEGCAP) deg = DEGCAP;
  for (int base = 0; base < deg; base += 64){
    int e = base + t;
    if (e < deg){
      int col = csr_src[beg+e];
      int eid = csr_eid[beg+e];
      float s = ssrc[col] + sdst[n] + (eid < 0 ? seloop[n] : se[eid]);
      s = (s > 0.f) ? s : 0.2f*s;
      s_al[e] = s;
      s_col[e] = col;
    }
  }
  __syncthreads();
  if (t == 0){
    float m = -1e30f;
    for (int e = 0; e < deg; ++e) m = fmaxf(m, s_al[e]);
    float z = 0.f;
    for (int e = 0; e < deg; ++e){ float ex = expf(s_al[e]-m); s_al[e] = ex; z += ex; }
    float inv = 1.0f/(z + 1e-16f);
    for (int e = 0; e < deg; ++e) s_al[e] *= inv;
  }
  __syncthreads();
  float acc = 0.f;
  for (int e = 0; e < deg; ++e) acc += s_al[e] * xs[(size_t)s_col[e]*64 + t];
  out[(size_t)n*64 + t] = fmaxf(acc + bias[t], 0.f);
}

// ---------------- pooling (batch is sorted) ----------------
__global__ __launch_bounds__(64) void k_pool(const float* __restrict__ h, const int* __restrict__ batch,
                                             float* __restrict__ pooled, int* __restrict__ cntg){
  int l = threadIdx.x;
  int start = blockIdx.x * 256;
  if (start >= NNODES) return;
  int endn = min(start + 256, NNODES);
  float acc = 0.f;
  int curg = batch[start];
  int run = 0;
  for (int n = start; n < endn; ++n){
    int g = batch[n];
    if (g != curg){
      atomicAdd(&pooled[curg*64+l], acc);
      if (l == 0) atomicAdd(&cntg[curg], run);
      acc = 0.f; run = 0; curg = g;
    }
    acc += h[(size_t)n*64 + l];
    ++run;
  }
  atomicAdd(&pooled[curg*64+l], acc);
  if (l == 0) atomicAdd(&cntg[curg], run);
}

// ---------------- final FFN + softmax ----------------
__global__ void k_ffn(const float* __restrict__ pooled, const int* __restrict__ cntg,
                      const float* __restrict__ og,
                      const float* __restrict__ Wf1, const float* __restrict__ bf1,
                      const float* __restrict__ Wf2, const float* __restrict__ bf2,
                      float* __restrict__ out){
  __shared__ float z[135];
  __shared__ float z1[67];
  __shared__ float o2[2];
  int g = blockIdx.x, t = threadIdx.x;
  if (t < 64) z[t] = pooled[g*64+t] * (1.0f/fmaxf((float)cntg[g], 1.0f));
  else if (t < 135) z[t] = og[g*OGW + (t-64)];
  __syncthreads();
  if (t < 67){
    float s = bf1[t];
    for (int d = 0; d < 135; ++d) s += z[d]*Wf1[d*67+t];
    z1[t] = fmaxf(s, 0.f);
  }
  __syncthreads();
  if (t < 2){
    float s = bf2[t];
    for (int j = 0; j < 67; ++j) s += z1[j]*Wf2[j*2+t];
    o2[t] = s;
  }
  __syncthreads();
  if (t == 0){
    float m = fmaxf(o2[0], o2[1]);
    float e0 = expf(o2[0]-m), e1 = expf(o2[1]-m);
    float inv = 1.0f/(e0+e1);
    out[g*2+0] = e0*inv;
    out[g*2+1] = e1*inv;
  }
}

extern "C" void kernel_launch(void* const* d_in, const int* in_sizes, int n_in,
                              void* d_out, int out_size, void* d_ws, size_t ws_size,
                              hipStream_t stream){
  const float* x     = (const float*)d_in[0];
  const int*   ei    = (const int*)d_in[1];
  const float* eattr = (const float*)d_in[2];
  const int*   batch = (const int*)d_in[3];
  const float* W1  = (const float*)d_in[4];
  const float* We1 = (const float*)d_in[5];
  const float* as1 = (const float*)d_in[6];
  const float* ad1 = (const float*)d_in[7];
  const float* ae1 = (const float*)d_in[8];
  const float* b1  = (const float*)d_in[9];
  const float* W2  = (const float*)d_in[10];
  const float* We2 = (const float*)d_in[11];
  const float* as2 = (const float*)d_in[12];
  const float* ad2 = (const float*)d_in[13];
  const float* ae2 = (const float*)d_in[14];
  const float* b2  = (const float*)d_in[15];
  const float* W3  = (const float*)d_in[16];
  const float* We3 = (const float*)d_in[17];
  const float* as3 = (const float*)d_in[18];
  const float* ad3 = (const float*)d_in[19];
  const float* ae3 = (const float*)d_in[20];
  const float* b3  = (const float*)d_in[21];
  const float* Wf1 = (const float*)d_in[22];
  const float* bf1 = (const float*)d_in[23];
  const float* Wf2 = (const float*)d_in[24];
  const float* bf2 = (const float*)d_in[25];
  (void)in_sizes; (void)n_in; (void)out_size; (void)ws_size;
  const int* src = ei;
  const int* dst = ei + NEDGES;
  float* out = (float*)d_out;

  char* base = (char*)d_ws;
  size_t woff = 0;
  auto alloc = [&](size_t bytes)->char*{
    char* p = base + woff;
    woff += (bytes + 255) & ~(size_t)255;
    return p;
  };
  float* bufA   = (float*)alloc((size_t)NNODES*512*4);   // xs (f32) per layer
  u16*   hb     = (u16*)  alloc((size_t)NNODES*512*2);   // bf16 activations h1/h2
  u16*   xb     = (u16*)  alloc((size_t)NNODES*64*2);    // bf16 x
  u16*   Wt1    = (u16*)  alloc((size_t)64*512*2);
  u16*   Wt2    = (u16*)  alloc((size_t)512*512*2);
  u16*   Wt3    = (u16*)  alloc((size_t)512*64*2);
  float* se     = (float*)alloc((size_t)NEDGES*4*4);
  float* seloop = (float*)alloc((size_t)NNODES*4*4);
  float* ssrc   = (float*)alloc((size_t)NNODES*4*4);
  float* sdst   = (float*)alloc((size_t)NNODES*4*4);
  float* ve     = (float*)alloc(72*4*4);
  int*   deg    = (int*)alloc((size_t)NNODES*4);
  int*   cnt    = (int*)alloc((size_t)NNODES*4);
  int*   csroff = (int*)alloc((size_t)(NNODES+1)*4);
  int*   csrsrc = (int*)alloc((size_t)NEA*4);
  int*   csreid = (int*)alloc((size_t)NEA*4);
  float* ogpart = (float*)alloc((size_t)128*NG*OGW*4);
  float* og     = (float*)alloc((size_t)NG*OGW*4);
  float* pooled = (float*)alloc((size_t)NG*64*4);
  int*   cntg   = (int*)alloc((size_t)NG*4);
  float* xs3 = bufA;                       // layer-3 xs (f32, 50000x64)
  float* h3  = bufA + (size_t)NNODES*64;   // disjoint region of bufA

  hipMemsetAsync(deg,    0, (size_t)NNODES*4, stream);
  hipMemsetAsync(cnt,    0, (size_t)NNODES*4, stream);
  hipMemsetAsync(pooled, 0, (size_t)NG*64*4, stream);
  hipMemsetAsync(cntg,   0, (size_t)NG*4, stream);

  // casts
  k_cast4 <<<ceil_div(NNODES*64/4,256),256,0,stream>>>(x, xb, NNODES*64/4);
  k_castWt<<<ceil_div(64*512,256),256,0,stream>>>(W1, Wt1, 64, 512);
  k_castWt<<<ceil_div(512*512,256),256,0,stream>>>(W2, Wt2, 512, 512);
  k_castWt<<<ceil_div(512*64,256),256,0,stream>>>(W3, Wt3, 512, 64);

  // CSR build (dst-grouped, self loop in last slot of each segment)
  k_deg <<<ceil_div(NEDGES,256),256,0,stream>>>(dst, deg);
  k_scan<<<1,1024,0,stream>>>(deg, csroff);
  k_fill<<<ceil_div(NEDGES,256),256,0,stream>>>(src, dst, csroff, cnt, csrsrc, csreid);
  k_self<<<ceil_div(NNODES,256),256,0,stream>>>(csroff, csrsrc, csreid);

  // 1-gram feature
  k_og      <<<128,512,0,stream>>>(eattr, src, batch, ogpart);
  k_ogreduce<<<ceil_div(NG*OGW,256),256,0,stream>>>(ogpart, og, 128);
  k_ognorm  <<<1,128,0,stream>>>(og);

  dim3 gM8(ceil_div(NNODES,128), 8);
  dim3 gM1(ceil_div(NNODES,128), 1);

  // ---- layer 1 ----
  k_gemm_bf16<<<gM8,256,0,stream>>>(xb, Wt1, bufA, NNODES, 64, 512);
  k_ve  <<<2,256,0,stream>>>(We1, ae1, ve, 4, 128);
  k_se<4>    <<<ceil_div(NEDGES,256),256,0,stream>>>(eattr, ve, se);
  k_seloop<4><<<ceil_div(NNODES,256),256,0,stream>>>(csroff, csreid, se, seloop);
  k_satt512  <<<ceil_div(NNODES,4),256,0,stream>>>(bufA, as1, ad1, ssrc, sdst);
  k_agg12    <<<NNODES,128,0,stream>>>(bufA, csroff, csrsrc, csreid, ssrc, sdst, se, seloop, b1, hb);

  // ---- layer 2 ----
  k_gemm_bf16<<<gM8,256,0,stream>>>(hb, Wt2, bufA, NNODES, 512, 512);
  k_ve  <<<2,256,0,stream>>>(We2, ae2, ve, 4, 128);
  k_se<4>    <<<ceil_div(NEDGES,256),256,0,stream>>>(eattr, ve, se);
  k_seloop<4><<<ceil_div(NNODES,256),256,0,stream>>>(csroff, csreid, se, seloop);
  k_satt512  <<<ceil_div(NNODES,4),256,0,stream>>>(bufA, as2, ad2, ssrc, sdst);
  k_agg12    <<<NNODES,128,0,stream>>>(bufA, csroff, csrsrc, csreid, ssrc, sdst, se, seloop, b2, hb);

  // ---- layer 3 (H=1, C=64) ----
  k_gemm_bf16<<<gM1,256,0,stream>>>(hb, Wt3, xs3, NNODES, 512, 64);
  k_ve  <<<1,128,0,stream>>>(We3, ae3, ve, 1, 64);
  k_se<1>    <<<ceil_div(NEDGES,256),256,0,stream>>>(eattr, ve, se);
  k_seloop<1><<<ceil_div(NNODES,256),256,0,stream>>>(csroff, csreid, se, seloop);
  k_satt64   <<<ceil_div(NNODES,4),256,0,stream>>>(xs3, as3, ad3, ssrc, sdst);
  k_agg3     <<<NNODES,64,0,stream>>>(xs3, csroff, csrsrc, csreid, ssrc, sdst, se, seloop, b3, h3);

  // ---- pool + FFN + softmax ----
  k_pool<<<ceil_div(NNODES,256),64,0,stream>>>(h3, batch, pooled, cntg);
  k_ffn <<<NG,192,0,stream>>>(pooled, cntg, og, Wf1, bf1, Wf2, bf2, out);
}

// Round 3
// 970.957 us; speedup vs baseline: 2.0248x; 1.4038x over previous
//
#include <hip/hip_runtime.h>

#define NNODES 50000
#define NEDGES 400000
#define NEA    450000
#define NG     128
#define DEGCAP 96
#define OGW    72   // padded og row stride (71 used)

typedef unsigned short u16;
typedef unsigned int   u32;
typedef __attribute__((ext_vector_type(8))) short short8v;
typedef __attribute__((ext_vector_type(4))) float f32x4;

static inline int ceil_div(int a, int b){ return (a + b - 1)/b; }

__device__ __forceinline__ u16 f2bf(float f){
  u32 u = __builtin_bit_cast(u32, f);
  u = (u + 0x7fffu + ((u >> 16) & 1u)) >> 16;   // RNE
  return (u16)u;
}
__device__ __forceinline__ float bf2f(u16 b){
  return __builtin_bit_cast(float, (u32)b << 16);
}

// ---------------- casts ----------------
__global__ void k_cast4(const float* __restrict__ in, u16* __restrict__ outb, int n4){
  int i = blockIdx.x*blockDim.x + threadIdx.x;
  if (i >= n4) return;
  float4 v = ((const float4*)in)[i];
  ((ushort4*)outb)[i] = make_ushort4(f2bf(v.x), f2bf(v.y), f2bf(v.z), f2bf(v.w));
}

// W [K,N] f32 -> Wt [N,K] bf16 (transposed for coalesced B staging)
__global__ void k_castWt(const float* __restrict__ W, u16* __restrict__ Wt, int K, int Nn){
  int idx = blockIdx.x*blockDim.x + threadIdx.x;
  if (idx >= K*Nn) return;
  int n = idx / K, k = idx - n*K;
  Wt[idx] = f2bf(W[(size_t)k*Nn + n]);
}

// ---------------- CSR build ----------------
__global__ void k_deg(const int* __restrict__ dst, int* __restrict__ deg){
  int e = blockIdx.x*blockDim.x + threadIdx.x;
  if (e < NEDGES) atomicAdd(&deg[dst[e]], 1);
}

__global__ __launch_bounds__(1024) void k_scan(const int* __restrict__ deg, int* __restrict__ off){
  __shared__ int s[1024];
  const int CH = (NNODES + 1023)/1024;   // 49
  int t = threadIdx.x;
  int i0 = t*CH, i1 = min(i0 + CH, NNODES);
  int loc = 0;
  for (int i = i0; i < i1; ++i) loc += deg[i] + 1;
  s[t] = loc; __syncthreads();
  for (int o = 1; o < 1024; o <<= 1){
    int v = (t >= o) ? s[t-o] : 0;
    __syncthreads();
    s[t] += v;
    __syncthreads();
  }
  int excl = s[t] - loc;
  for (int i = i0; i < i1; ++i){ off[i] = excl; excl += deg[i] + 1; }
  if (t == 1023) off[NNODES] = s[1023];
}

__global__ void k_fill(const int* __restrict__ src, const int* __restrict__ dst,
                       const int* __restrict__ off, int* __restrict__ cnt,
                       int* __restrict__ csr_src, int* __restrict__ csr_eid){
  int e = blockIdx.x*blockDim.x + threadIdx.x;
  if (e >= NEDGES) return;
  int d = dst[e];
  int p = off[d] + atomicAdd(&cnt[d], 1);
  csr_src[p] = src[e];
  csr_eid[p] = e;
}

__global__ void k_self(const int* __restrict__ off, int* __restrict__ csr_src, int* __restrict__ csr_eid){
  int n = blockIdx.x*blockDim.x + threadIdx.x;
  if (n >= NNODES) return;
  int p = off[n+1] - 1;
  csr_src[p] = n;
  csr_eid[p] = -1;
}

// ---------------- og (1-gram) ----------------
__global__ void k_gb(const int* __restrict__ src, const int* __restrict__ batch, int* __restrict__ gb){
  int e = blockIdx.x*blockDim.x + threadIdx.x;
  if (e < NEDGES) gb[e] = batch[src[e]];
}

#define OGBLK 512
__global__ __launch_bounds__(512) void k_og(const float* __restrict__ attr, const int* __restrict__ gb,
                                            float* __restrict__ partials){
  __shared__ float bins[NG*OGW];
  int t = threadIdx.x;
  for (int i = t; i < NG*OGW; i += 512) bins[i] = 0.f;
  __syncthreads();
  int lane = t & 63, w = t >> 6;    // 8 waves
  const int EPB = (NEDGES + OGBLK - 1)/OGBLK;
  int e0 = blockIdx.x*EPB, e1 = min(e0 + EPB, NEDGES);
  for (int eb = e0 + w; eb < e1; eb += 8*4){
    int bgs[4]; float va[4], vb[4];
    #pragma unroll
    for (int u = 0; u < 4; ++u){
      int e = eb + u*8;
      bool ok = (e < e1);
      bgs[u] = ok ? gb[e] : -1;
      va[u]  = ok ? attr[(size_t)e*72 + lane] : 0.f;
      vb[u]  = (ok && lane < 7) ? attr[(size_t)e*72 + 64 + lane] : 0.f;
    }
    #pragma unroll
    for (int u = 0; u < 4; ++u){
      if (bgs[u] >= 0){
        atomicAdd(&bins[bgs[u]*OGW + lane], va[u]);
        if (lane < 7) atomicAdd(&bins[bgs[u]*OGW + 64 + lane], vb[u]);
      }
    }
  }
  __syncthreads();
  for (int i = t; i < NG*OGW; i += 512)
    partials[(size_t)blockIdx.x*NG*OGW + i] = bins[i];
}

__global__ void k_ogreduce(const float* __restrict__ partials, float* __restrict__ og, int nb){
  int i = blockIdx.x*blockDim.x + threadIdx.x;
  if (i >= NG*OGW) return;
  float s = 0.f;
  for (int b = 0; b < nb; ++b) s += partials[(size_t)b*NG*OGW + i];
  og[i] = s;
}

__global__ void k_ognorm(float* __restrict__ og){
  int g = threadIdx.x;
  if (g >= NG) return;
  float s = 0.f;
  for (int k = 0; k < 71; ++k){ float v = og[g*OGW+k]; s += v*v; }
  float scale = 1.0f / fmaxf(sqrtf(s), 1e-12f);
  for (int k = 0; k < 71; ++k) og[g*OGW+k] *= scale;
}

// ---------------- bf16 MFMA GEMM: C[M,Nn] = A[M,K] @ Bt[Nn,K]^T ----------------
template<bool BFOUT>
__global__ __launch_bounds__(256) void k_gemm_bf16(const u16* __restrict__ A,
    const u16* __restrict__ Bt, void* __restrict__ Cv, int M, int K, int Nn){
  __shared__ __align__(16) u16 As[128*32];
  __shared__ __align__(16) u16 Bs[64*32];
  const int tid = threadIdx.x;
  const int wid = tid >> 6, lane = tid & 63;
  const int l15 = lane & 15, kslot = lane >> 4;
  const int m0 = blockIdx.x * 128, n0 = blockIdx.y * 64;
  f32x4 acc[2][4];
  #pragma unroll
  for (int mi = 0; mi < 2; ++mi)
    #pragma unroll
    for (int ni = 0; ni < 4; ++ni)
      acc[mi][ni] = (f32x4){0.f,0.f,0.f,0.f};

  for (int kt = 0; kt < K; kt += 32){
    #pragma unroll
    for (int i = 0; i < 2; ++i){
      int chunk = tid + i*256;
      int row = chunk >> 2, c16 = chunk & 3;
      uint4 v = make_uint4(0u,0u,0u,0u);
      int grow = m0 + row;
      if (grow < M) v = *(const uint4*)(A + (size_t)grow*K + kt + c16*8);
      *(uint4*)(&As[row*32 + ((c16*8) ^ ((row&3)<<3))]) = v;
    }
    {
      int row = tid >> 2, c16 = tid & 3;
      uint4 v = *(const uint4*)(Bt + (size_t)(n0+row)*K + kt + c16*8);
      *(uint4*)(&Bs[row*32 + ((c16*8) ^ ((row&3)<<3))]) = v;
    }
    __syncthreads();
    short8v a[2], b[4];
    #pragma unroll
    for (int mi = 0; mi < 2; ++mi){
      int r = wid*32 + mi*16 + l15;
      a[mi] = *(const short8v*)(&As[r*32 + ((kslot*8) ^ ((r&3)<<3))]);
    }
    #pragma unroll
    for (int ni = 0; ni < 4; ++ni){
      int c = ni*16 + l15;
      b[ni] = *(const short8v*)(&Bs[c*32 + ((kslot*8) ^ ((c&3)<<3))]);
    }
    #pragma unroll
    for (int mi = 0; mi < 2; ++mi)
      #pragma unroll
      for (int ni = 0; ni < 4; ++ni)
        acc[mi][ni] = __builtin_amdgcn_mfma_f32_16x16x32_bf16(a[mi], b[ni], acc[mi][ni], 0, 0, 0);
    __syncthreads();
  }
  #pragma unroll
  for (int mi = 0; mi < 2; ++mi){
    #pragma unroll
    for (int ni = 0; ni < 4; ++ni){
      #pragma unroll
      for (int r = 0; r < 4; ++r){
        int grow = m0 + wid*32 + mi*16 + kslot*4 + r;   // row=(lane>>4)*4+reg (m89/m91)
        if (grow < M){
          size_t idx = (size_t)grow*Nn + n0 + ni*16 + l15;
          if (BFOUT) ((u16*)Cv)[idx] = f2bf(acc[mi][ni][r]);
          else       ((float*)Cv)[idx] = acc[mi][ni][r];
        }
      }
    }
  }
}

// ---------------- attention scalars ----------------
// veall layout: [k=0..71][9]: cols 0-3 layer1 heads, 4-7 layer2 heads, 8 layer3
__global__ void k_ve(const float* __restrict__ We, const float* __restrict__ ae,
                     float* __restrict__ veall, int H, int C, int base){
  int t = blockIdx.x*blockDim.x + threadIdx.x;
  if (t >= 72*H) return;
  int k = t / H, h = t - k*H;
  const float* wrow = We + (size_t)k*H*C + (size_t)h*C;
  const float* arow = ae + (size_t)h*C;
  float s = 0.f;
  for (int c = 0; c < C; ++c) s += wrow[c]*arow[c];
  veall[k*9 + base + h] = s;
}

// all 9 edge-score scalars in one eattr pass
__global__ __launch_bounds__(256) void k_se_all(const float* __restrict__ attr,
    const float* __restrict__ veall, float* __restrict__ se){
  __shared__ float vel[72*9];
  for (int i = threadIdx.x; i < 72*9; i += blockDim.x) vel[i] = veall[i];
  __syncthreads();
  int e = blockIdx.x*blockDim.x + threadIdx.x;
  if (e >= NEDGES) return;
  const float4* row = (const float4*)(attr + (size_t)e*72);
  float s[9];
  #pragma unroll
  for (int j = 0; j < 9; ++j) s[j] = 0.f;
  #pragma unroll
  for (int kk = 0; kk < 18; ++kk){
    float4 a = row[kk];
    #pragma unroll
    for (int j = 0; j < 9; ++j)
      s[j] += a.x*vel[(kk*4+0)*9+j] + a.y*vel[(kk*4+1)*9+j]
            + a.z*vel[(kk*4+2)*9+j] + a.w*vel[(kk*4+3)*9+j];
  }
  #pragma unroll
  for (int j = 0; j < 9; ++j) se[(size_t)e*9+j] = s[j];
}

__global__ void k_seloop_all(const int* __restrict__ off, const int* __restrict__ csr_eid,
                             const float* __restrict__ se, float* __restrict__ seloop){
  int n = blockIdx.x*blockDim.x + threadIdx.x;
  if (n >= NNODES) return;
  int beg = off[n];
  int dr = off[n+1] - 1 - beg;
  float s[9];
  #pragma unroll
  for (int j = 0; j < 9; ++j) s[j] = 0.f;
  for (int p = beg; p < beg+dr; ++p){
    int eid = csr_eid[p];
    #pragma unroll
    for (int j = 0; j < 9; ++j) s[j] += se[(size_t)eid*9+j];
  }
  float inv = 1.0f / fmaxf((float)dr, 1.0f);
  #pragma unroll
  for (int j = 0; j < 9; ++j) seloop[(size_t)n*9+j] = s[j]*inv;
}

// per-node src/dst scalars from bf16 xs (H=4,C=128, row=512)
__global__ void k_satt512(const u16* __restrict__ xs, const float* __restrict__ a_s,
                          const float* __restrict__ a_d,
                          float* __restrict__ ssrc, float* __restrict__ sdst){
  int wid = threadIdx.x >> 6, lane = threadIdx.x & 63;
  int n = blockIdx.x*4 + wid;
  if (n >= NNODES) return;
  short8v v = *(const short8v*)(xs + (size_t)n*512 + lane*8);
  float ps = 0.f, pd = 0.f;
  #pragma unroll
  for (int q = 0; q < 8; ++q){
    float f = bf2f((u16)v[q]);
    int c = lane*8 + q;
    ps += f * a_s[c];
    pd += f * a_d[c];
  }
  for (int m = 8; m >= 1; m >>= 1){ ps += __shfl_xor(ps,m); pd += __shfl_xor(pd,m); }
  if ((lane & 15) == 0){ ssrc[n*4 + (lane>>4)] = ps; sdst[n*4 + (lane>>4)] = pd; }
}

// H=1, C=64 (f32 xs3)
__global__ void k_satt64(const float* __restrict__ xs, const float* __restrict__ a_s,
                         const float* __restrict__ a_d,
                         float* __restrict__ ssrc, float* __restrict__ sdst){
  int wid = threadIdx.x >> 6, lane = threadIdx.x & 63;
  int n = blockIdx.x*4 + wid;
  if (n >= NNODES) return;
  float v = xs[(size_t)n*64 + lane];
  float ps = v*a_s[lane], pd = v*a_d[lane];
  for (int m = 32; m >= 1; m >>= 1){ ps += __shfl_xor(ps,m); pd += __shfl_xor(pd,m); }
  if (lane == 0){ ssrc[n] = ps; sdst[n] = pd; }
}

// ---------------- aggregation: layers 1&2 (H=4,C=128), bf16 in/out ----------------
__global__ __launch_bounds__(128) void k_agg12(const u16* __restrict__ xs,
    const int* __restrict__ off, const int* __restrict__ csr_src, const int* __restrict__ csr_eid,
    const float* __restrict__ ssrc, const float* __restrict__ sdst,
    const float* __restrict__ se, const float* __restrict__ seloop, int soff,
    const float* __restrict__ bias, u16* __restrict__ out){
  __shared__ float s_al[DEGCAP][4];
  __shared__ int s_col[DEGCAP];
  int n = blockIdx.x;
  int t = threadIdx.x;
  int beg = off[n];
  int deg = off[n+1] - beg;
  if (deg > DEGCAP) deg = DEGCAP;
  for (int base = 0; base < deg; base += 32){
    int e = base + (t>>2);
    int h = t & 3;
    if (e < deg){
      int col = csr_src[beg+e];
      int eid = csr_eid[beg+e];
      float s = ssrc[col*4+h] + sdst[n*4+h]
              + (eid < 0 ? seloop[(size_t)n*9+soff+h] : se[(size_t)eid*9+soff+h]);
      s = (s > 0.f) ? s : 0.2f*s;
      s_al[e][h] = s;
      if (h == 0) s_col[e] = col;
    }
  }
  __syncthreads();
  if (t < 4){
    float m = -1e30f;
    for (int e = 0; e < deg; ++e) m = fmaxf(m, s_al[e][t]);
    float z = 0.f;
    for (int e = 0; e < deg; ++e){ float ex = expf(s_al[e][t]-m); s_al[e][t] = ex; z += ex; }
    float inv = 1.0f/(z + 1e-16f);
    for (int e = 0; e < deg; ++e) s_al[e][t] *= inv;
  }
  __syncthreads();
  float4 acc = make_float4(0.f,0.f,0.f,0.f);
  int hh = t >> 5;
  for (int e = 0; e < deg; ++e){
    float a = s_al[e][hh];
    ushort4 v = ((const ushort4*)(xs + (size_t)s_col[e]*512))[t];
    acc.x += a*bf2f(v.x); acc.y += a*bf2f(v.y); acc.z += a*bf2f(v.z); acc.w += a*bf2f(v.w);
  }
  float4 b4 = ((const float4*)bias)[t];
  float ox = fmaxf(acc.x + b4.x, 0.f);
  float oy = fmaxf(acc.y + b4.y, 0.f);
  float oz = fmaxf(acc.z + b4.z, 0.f);
  float ow = fmaxf(acc.w + b4.w, 0.f);
  ((ushort4*)(out + (size_t)n*512))[t] = make_ushort4(f2bf(ox), f2bf(oy), f2bf(oz), f2bf(ow));
}

// ---------------- aggregation: layer 3 (H=1,C=64), f32 ----------------
__global__ __launch_bounds__(64) void k_agg3(const float* __restrict__ xs,
    const int* __restrict__ off, const int* __restrict__ csr_src, const int* __restrict__ csr_eid,
    const float* __restrict__ ssrc, const float* __restrict__ sdst,
    const float* __restrict__ se, const float* __restrict__ seloop,
    const float* __restrict__ bias, float* __restrict__ out){
  __shared__ float s_al[DEGCAP];
  __shared__ int s_col[DEGCAP];
  int n = blockIdx.x;
  int t = threadIdx.x;
  int beg = off[n];
  int deg = off[n+1] - beg;
  if (deg > DEGCAP) deg = DEGCAP;
  for (int base = 0; base < deg; base += 64){
    int e = base + t;
    if (e < deg){
      int col = csr_src[beg+e];
      int eid = csr_eid[beg+e];
      float s = ssrc[col] + sdst[n]
              + (eid < 0 ? seloop[(size_t)n*9+8] : se[(size_t)eid*9+8]);
      s = (s > 0.f) ? s : 0.2f*s;
      s_al[e] = s;
      s_col[e] = col;
    }
  }
  __syncthreads();
  if (t == 0){
    float m = -1e30f;
    for (int e = 0; e < deg; ++e) m = fmaxf(m, s_al[e]);
    float z = 0.f;
    for (int e = 0; e < deg; ++e){ float ex = expf(s_al[e]-m); s_al[e] = ex; z += ex; }
    float inv = 1.0f/(z + 1e-16f);
    for (int e = 0; e < deg; ++e) s_al[e] *= inv;
  }
  __syncthreads();
  float acc = 0.f;
  for (int e = 0; e < deg; ++e) acc += s_al[e] * xs[(size_t)s_col[e]*64 + t];
  out[(size_t)n*64 + t] = fmaxf(acc + bias[t], 0.f);
}

// ---------------- pooling (batch is sorted) ----------------
__global__ __launch_bounds__(64) void k_pool(const float* __restrict__ h, const int* __restrict__ batch,
                                             float* __restrict__ pooled, int* __restrict__ cntg){
  int l = threadIdx.x;
  int start = blockIdx.x * 256;
  if (start >= NNODES) return;
  int endn = min(start + 256, NNODES);
  float acc = 0.f;
  int curg = batch[start];
  int run = 0;
  for (int n = start; n < endn; ++n){
    int g = batch[n];
    if (g != curg){
      atomicAdd(&pooled[curg*64+l], acc);
      if (l == 0) atomicAdd(&cntg[curg], run);
      acc = 0.f; run = 0; curg = g;
    }
    acc += h[(size_t)n*64 + l];
    ++run;
  }
  atomicAdd(&pooled[curg*64+l], acc);
  if (l == 0) atomicAdd(&cntg[curg], run);
}

// ---------------- final FFN + softmax ----------------
__global__ void k_ffn(const float* __restrict__ pooled, const int* __restrict__ cntg,
                      const float* __restrict__ og,
                      const float* __restrict__ Wf1, const float* __restrict__ bf1,
                      const float* __restrict__ Wf2, const float* __restrict__ bf2,
                      float* __restrict__ out){
  __shared__ float z[135];
  __shared__ float z1[67];
  __shared__ float o2[2];
  int g = blockIdx.x, t = threadIdx.x;
  if (t < 64) z[t] = pooled[g*64+t] * (1.0f/fmaxf((float)cntg[g], 1.0f));
  else if (t < 135) z[t] = og[g*OGW + (t-64)];
  __syncthreads();
  if (t < 67){
    float s = bf1[t];
    for (int d = 0; d < 135; ++d) s += z[d]*Wf1[d*67+t];
    z1[t] = fmaxf(s, 0.f);
  }
  __syncthreads();
  if (t < 2){
    float s = bf2[t];
    for (int j = 0; j < 67; ++j) s += z1[j]*Wf2[j*2+t];
    o2[t] = s;
  }
  __syncthreads();
  if (t == 0){
    float m = fmaxf(o2[0], o2[1]);
    float e0 = expf(o2[0]-m), e1 = expf(o2[1]-m);
    float inv = 1.0f/(e0+e1);
    out[g*2+0] = e0*inv;
    out[g*2+1] = e1*inv;
  }
}

extern "C" void kernel_launch(void* const* d_in, const int* in_sizes, int n_in,
                              void* d_out, int out_size, void* d_ws, size_t ws_size,
                              hipStream_t stream){
  const float* x     = (const float*)d_in[0];
  const int*   ei    = (const int*)d_in[1];
  const float* eattr = (const float*)d_in[2];
  const int*   batch = (const int*)d_in[3];
  const float* W1  = (const float*)d_in[4];
  const float* We1 = (const float*)d_in[5];
  const float* as1 = (const float*)d_in[6];
  const float* ad1 = (const float*)d_in[7];
  const float* ae1 = (const float*)d_in[8];
  const float* b1  = (const float*)d_in[9];
  const float* W2  = (const float*)d_in[10];
  const float* We2 = (const float*)d_in[11];
  const float* as2 = (const float*)d_in[12];
  const float* ad2 = (const float*)d_in[13];
  const float* ae2 = (const float*)d_in[14];
  const float* b2  = (const float*)d_in[15];
  const float* W3  = (const float*)d_in[16];
  const float* We3 = (const float*)d_in[17];
  const float* as3 = (const float*)d_in[18];
  const float* ad3 = (const float*)d_in[19];
  const float* ae3 = (const float*)d_in[20];
  const float* b3  = (const float*)d_in[21];
  const float* Wf1 = (const float*)d_in[22];
  const float* bf1 = (const float*)d_in[23];
  const float* Wf2 = (const float*)d_in[24];
  const float* bf2 = (const float*)d_in[25];
  (void)in_sizes; (void)n_in; (void)out_size; (void)ws_size;
  const int* src = ei;
  const int* dst = ei + NEDGES;
  float* out = (float*)d_out;

  char* base = (char*)d_ws;
  size_t woff = 0;
  auto alloc = [&](size_t bytes)->char*{
    char* p = base + woff;
    woff += (bytes + 255) & ~(size_t)255;
    return p;
  };
  u16*   xsb    = (u16*)  alloc((size_t)NNODES*512*2);   // bf16 xs (layers 1,2)
  u16*   hb     = (u16*)  alloc((size_t)NNODES*512*2);   // bf16 activations h1/h2
  float* xs3    = (float*)alloc((size_t)NNODES*64*4);    // f32 xs layer 3
  float* h3     = (float*)alloc((size_t)NNODES*64*4);
  u16*   xb     = (u16*)  alloc((size_t)NNODES*64*2);
  u16*   Wt1    = (u16*)  alloc((size_t)64*512*2);
  u16*   Wt2    = (u16*)  alloc((size_t)512*512*2);
  u16*   Wt3    = (u16*)  alloc((size_t)512*64*2);
  float* se     = (float*)alloc((size_t)NEDGES*9*4);
  float* seloop = (float*)alloc((size_t)NNODES*9*4);
  float* ssrc   = (float*)alloc((size_t)NNODES*4*4);
  float* sdst   = (float*)alloc((size_t)NNODES*4*4);
  float* veall  = (float*)alloc(72*9*4);
  int*   gb     = (int*)alloc((size_t)NEDGES*4);
  int*   deg    = (int*)alloc((size_t)NNODES*4);
  int*   cnt    = (int*)alloc((size_t)NNODES*4);
  int*   csroff = (int*)alloc((size_t)(NNODES+1)*4);
  int*   csrsrc = (int*)alloc((size_t)NEA*4);
  int*   csreid = (int*)alloc((size_t)NEA*4);
  float* ogpart = (float*)alloc((size_t)OGBLK*NG*OGW*4);
  float* og     = (float*)alloc((size_t)NG*OGW*4);
  float* pooled = (float*)alloc((size_t)NG*64*4);
  int*   cntg   = (int*)alloc((size_t)NG*4);

  hipMemsetAsync(deg,    0, (size_t)NNODES*4, stream);
  hipMemsetAsync(cnt,    0, (size_t)NNODES*4, stream);
  hipMemsetAsync(pooled, 0, (size_t)NG*64*4, stream);
  hipMemsetAsync(cntg,   0, (size_t)NG*4, stream);

  // casts
  k_cast4 <<<ceil_div(NNODES*64/4,256),256,0,stream>>>(x, xb, NNODES*64/4);
  k_castWt<<<ceil_div(64*512,256),256,0,stream>>>(W1, Wt1, 64, 512);
  k_castWt<<<ceil_div(512*512,256),256,0,stream>>>(W2, Wt2, 512, 512);
  k_castWt<<<ceil_div(512*64,256),256,0,stream>>>(W3, Wt3, 512, 64);

  // CSR build
  k_deg <<<ceil_div(NEDGES,256),256,0,stream>>>(dst, deg);
  k_scan<<<1,1024,0,stream>>>(deg, csroff);
  k_fill<<<ceil_div(NEDGES,256),256,0,stream>>>(src, dst, csroff, cnt, csrsrc, csreid);
  k_self<<<ceil_div(NNODES,256),256,0,stream>>>(csroff, csrsrc, csreid);

  // 1-gram feature
  k_gb      <<<ceil_div(NEDGES,256),256,0,stream>>>(src, batch, gb);
  k_og      <<<OGBLK,512,0,stream>>>(eattr, gb, ogpart);
  k_ogreduce<<<ceil_div(NG*OGW,256),256,0,stream>>>(ogpart, og, OGBLK);
  k_ognorm  <<<1,128,0,stream>>>(og);

  // edge scores for all 3 layers in one eattr pass
  k_ve<<<2,256,0,stream>>>(We1, ae1, veall, 4, 128, 0);
  k_ve<<<2,256,0,stream>>>(We2, ae2, veall, 4, 128, 4);
  k_ve<<<1,128,0,stream>>>(We3, ae3, veall, 1, 64, 8);
  k_se_all    <<<ceil_div(NEDGES,256),256,0,stream>>>(eattr, veall, se);
  k_seloop_all<<<ceil_div(NNODES,256),256,0,stream>>>(csroff, csreid, se, seloop);

  dim3 gM8(ceil_div(NNODES,128), 8);
  dim3 gM1(ceil_div(NNODES,128), 1);

  // ---- layer 1 ----
  k_gemm_bf16<true><<<gM8,256,0,stream>>>(xb, Wt1, xsb, NNODES, 64, 512);
  k_satt512<<<ceil_div(NNODES,4),256,0,stream>>>(xsb, as1, ad1, ssrc, sdst);
  k_agg12  <<<NNODES,128,0,stream>>>(xsb, csroff, csrsrc, csreid, ssrc, sdst, se, seloop, 0, b1, hb);

  // ---- layer 2 ----
  k_gemm_bf16<true><<<gM8,256,0,stream>>>(hb, Wt2, xsb, NNODES, 512, 512);
  k_satt512<<<ceil_div(NNODES,4),256,0,stream>>>(xsb, as2, ad2, ssrc, sdst);
  k_agg12  <<<NNODES,128,0,stream>>>(xsb, csroff, csrsrc, csreid, ssrc, sdst, se, seloop, 4, b2, hb);

  // ---- layer 3 (H=1, C=64) ----
  k_gemm_bf16<false><<<gM1,256,0,stream>>>(hb, Wt3, xs3, NNODES, 512, 64);
  k_satt64<<<ceil_div(NNODES,4),256,0,stream>>>(xs3, as3, ad3, ssrc, sdst);
  k_agg3  <<<NNODES,64,0,stream>>>(xs3, csroff, csrsrc, csreid, ssrc, sdst, se, seloop, b3, h3);

  // ---- pool + FFN + softmax ----
  k_pool<<<ceil_div(NNODES,256),64,0,stream>>>(h3, batch, pooled, cntg);
  k_ffn <<<NG,192,0,stream>>>(pooled, cntg, og, Wf1, bf1, Wf2, bf2, out);
}

// Round 4
// 876.628 us; speedup vs baseline: 2.2427x; 1.1076x over previous
//
#include <hip/hip_runtime.h>

#define NNODES 50000
#define NEDGES 400000
#define NEA    450000
#define NG     128
#define DEGCAP 96
#define OGW    72   // padded og row stride (71 used)

typedef unsigned short u16;
typedef unsigned int   u32;
typedef __attribute__((ext_vector_type(8))) short short8v;
typedef __attribute__((ext_vector_type(4))) float f32x4;

static inline int ceil_div(int a, int b){ return (a + b - 1)/b; }

__device__ __forceinline__ u16 f2bf(float f){
  u32 u = __builtin_bit_cast(u32, f);
  u = (u + 0x7fffu + ((u >> 16) & 1u)) >> 16;   // RNE
  return (u16)u;
}
__device__ __forceinline__ float bf2f(u16 b){
  return __builtin_bit_cast(float, (u32)b << 16);
}
__device__ __forceinline__ void gload_lds16(const u16* g, u16* l){
  __builtin_amdgcn_global_load_lds((const __attribute__((address_space(1))) void*)g,
                                   (__attribute__((address_space(3))) void*)l, 16, 0, 0);
}

// ---------------- casts ----------------
__global__ void k_cast4(const float* __restrict__ in, u16* __restrict__ outb, int n4){
  int i = blockIdx.x*blockDim.x + threadIdx.x;
  if (i >= n4) return;
  float4 v = ((const float4*)in)[i];
  ((ushort4*)outb)[i] = make_ushort4(f2bf(v.x), f2bf(v.y), f2bf(v.z), f2bf(v.w));
}

// W [K,N] f32 -> Wt [N,K] bf16
__global__ void k_castWt(const float* __restrict__ W, u16* __restrict__ Wt, int K, int Nn){
  int idx = blockIdx.x*blockDim.x + threadIdx.x;
  if (idx >= K*Nn) return;
  int n = idx / K, k = idx - n*K;
  Wt[idx] = f2bf(W[(size_t)k*Nn + n]);
}

// ---------------- CSR build ----------------
__global__ void k_deg(const int* __restrict__ dst, int* __restrict__ deg){
  int e = blockIdx.x*blockDim.x + threadIdx.x;
  if (e < NEDGES) atomicAdd(&deg[dst[e]], 1);
}

__global__ __launch_bounds__(1024) void k_scan(const int* __restrict__ deg, int* __restrict__ off){
  __shared__ int s[1024];
  const int CH = (NNODES + 1023)/1024;
  int t = threadIdx.x;
  int i0 = t*CH, i1 = min(i0 + CH, NNODES);
  int loc = 0;
  for (int i = i0; i < i1; ++i) loc += deg[i] + 1;
  s[t] = loc; __syncthreads();
  for (int o = 1; o < 1024; o <<= 1){
    int v = (t >= o) ? s[t-o] : 0;
    __syncthreads();
    s[t] += v;
    __syncthreads();
  }
  int excl = s[t] - loc;
  for (int i = i0; i < i1; ++i){ off[i] = excl; excl += deg[i] + 1; }
  if (t == 1023) off[NNODES] = s[1023];
}

__global__ void k_fill(const int* __restrict__ src, const int* __restrict__ dst,
                       const int* __restrict__ off, int* __restrict__ cnt,
                       int* __restrict__ csr_src, int* __restrict__ csr_eid){
  int e = blockIdx.x*blockDim.x + threadIdx.x;
  if (e >= NEDGES) return;
  int d = dst[e];
  int p = off[d] + atomicAdd(&cnt[d], 1);
  csr_src[p] = src[e];
  csr_eid[p] = e;
}

__global__ void k_self(const int* __restrict__ off, int* __restrict__ csr_src, int* __restrict__ csr_eid){
  int n = blockIdx.x*blockDim.x + threadIdx.x;
  if (n >= NNODES) return;
  int p = off[n+1] - 1;
  csr_src[p] = n;
  csr_eid[p] = -1;
}

// ---------------- og: graph-keyed counting sort + register segment-sum ----------------
__global__ void k_gb_hist(const int* __restrict__ src, const int* __restrict__ batch,
                          int* __restrict__ gb, int* __restrict__ gcnt){
  __shared__ int h[NG];
  int t = threadIdx.x;
  if (t < NG) h[t] = 0;
  __syncthreads();
  int e = blockIdx.x*blockDim.x + t;
  int g = -1;
  if (e < NEDGES){
    g = batch[src[e]];
    gb[e] = g;
    atomicAdd(&h[g], 1);
  }
  __syncthreads();
  if (t < NG && h[t]) atomicAdd(&gcnt[t], h[t]);
}

__global__ void k_gscan(const int* __restrict__ gcnt, int* __restrict__ goff, int* __restrict__ gcur){
  __shared__ int s[NG];
  int t = threadIdx.x;   // 128 threads
  int v = gcnt[t];
  s[t] = v; __syncthreads();
  for (int o = 1; o < NG; o <<= 1){
    int x = (t >= o) ? s[t-o] : 0;
    __syncthreads();
    s[t] += x;
    __syncthreads();
  }
  goff[t] = s[t] - v;
  gcur[t] = s[t] - v;
}

__global__ void k_gscatter(const int* __restrict__ gb, int* __restrict__ gcur,
                           int* __restrict__ sortedeid){
  __shared__ int lcnt[NG];
  __shared__ int lbase[NG];
  int t = threadIdx.x;
  if (t < NG) lcnt[t] = 0;
  __syncthreads();
  int e = blockIdx.x*blockDim.x + t;
  int g = -1, lr = 0;
  if (e < NEDGES){
    g = gb[e];
    lr = atomicAdd(&lcnt[g], 1);
  }
  __syncthreads();
  if (t < NG && lcnt[t]) lbase[t] = atomicAdd(&gcur[t], lcnt[t]);
  __syncthreads();
  if (e < NEDGES) sortedeid[lbase[g] + lr] = e;
}

// grid = NG*8 blocks, 256 threads (4 waves). Register accumulation, no LDS atomics.
__global__ __launch_bounds__(256) void k_og2(const float* __restrict__ attr,
    const int* __restrict__ goff, const int* __restrict__ gcnt,
    const int* __restrict__ sortedeid, float* __restrict__ og){
  __shared__ float red[4][OGW];
  int g = blockIdx.x >> 3, chunk = blockIdx.x & 7;
  int lane = threadIdx.x & 63, w = threadIdx.x >> 6;
  int beg = goff[g], cnt = gcnt[g];
  int cbeg = beg + ((cnt*chunk) >> 3);
  int cend = beg + ((cnt*(chunk+1)) >> 3);
  float acc0 = 0.f, acc1 = 0.f;
  for (int i = cbeg + w*4; i < cend; i += 16){
    int n4 = min(4, cend - i);
    int eids[4];
    #pragma unroll
    for (int u = 0; u < 4; ++u) eids[u] = (u < n4) ? sortedeid[i+u] : -1;
    #pragma unroll
    for (int u = 0; u < 4; ++u){
      if (eids[u] >= 0){
        acc0 += attr[(size_t)eids[u]*72 + lane];
        if (lane < 7) acc1 += attr[(size_t)eids[u]*72 + 64 + lane];
      }
    }
  }
  red[w][lane] = acc0;
  if (lane < 7) red[w][64+lane] = acc1;
  else if (lane == 63) red[w][71] = 0.f;
  __syncthreads();
  int t = threadIdx.x;
  if (t < 71){
    float s = red[0][t] + red[1][t] + red[2][t] + red[3][t];
    if (s != 0.f) atomicAdd(&og[g*OGW + t], s);
  }
}

__global__ void k_ognorm(float* __restrict__ og){
  int g = threadIdx.x;
  if (g >= NG) return;
  float s = 0.f;
  for (int k = 0; k < 71; ++k){ float v = og[g*OGW+k]; s += v*v; }
  float scale = 1.0f / fmaxf(sqrtf(s), 1e-12f);
  for (int k = 0; k < 71; ++k) og[g*OGW+k] *= scale;
}

// ---------------- m97-style bf16 MFMA GEMM: BM=BN=128, BK=64, global_load_lds ----------------
// A bf16 [M,K] row-major; Bt bf16 [Nn,K] row-major; C = A @ Bt^T.
// Swizzle: LDS row of 8x16B chunks; chunk c8 holds global k-chunk (c8 ^ (row&7)).
// FUSE_ATT: also emit ssrc/sdst per-node head dots (BN=128 == one head).
template<bool BFOUT, bool FUSE_ATT>
__global__ __launch_bounds__(256) void k_gemm128(const u16* __restrict__ A,
    const u16* __restrict__ Bt, void* __restrict__ Cv, int M, int K, int Nn,
    const float* __restrict__ a_s, const float* __restrict__ a_d,
    float* __restrict__ ssrc, float* __restrict__ sdst){
  __shared__ __align__(16) u16 As[128*64];
  __shared__ __align__(16) u16 Bs[128*64];
  const int tid = threadIdx.x;
  const int wid = tid >> 6, lane = tid & 63;
  const int l15 = lane & 15, kslot = lane >> 4;
  const int wr = wid >> 1, wc = wid & 1;
  const int m0 = blockIdx.x * 128, n0 = blockIdx.y * 128;
  f32x4 acc[4][4];
  #pragma unroll
  for (int mi = 0; mi < 4; ++mi)
    #pragma unroll
    for (int ni = 0; ni < 4; ++ni)
      acc[mi][ni] = (f32x4){0.f,0.f,0.f,0.f};

  for (int kt = 0; kt < K; kt += 64){
    #pragma unroll
    for (int r = 0; r < 4; ++r){
      int chunk = (r*4 + wid)*64 + lane;
      int row = chunk >> 3, c8 = chunk & 7;
      int srcc = c8 ^ (row & 7);
      int grow = m0 + row; if (grow > M-1) grow = M-1;
      gload_lds16(A + (size_t)grow*K + kt + srcc*8, &As[chunk*8]);
    }
    #pragma unroll
    for (int r = 0; r < 4; ++r){
      int chunk = (r*4 + wid)*64 + lane;
      int row = chunk >> 3, c8 = chunk & 7;
      int srcc = c8 ^ (row & 7);
      gload_lds16(Bt + (size_t)(n0+row)*K + kt + srcc*8, &Bs[chunk*8]);
    }
    __syncthreads();
    #pragma unroll
    for (int s = 0; s < 2; ++s){
      short8v a[4], b[4];
      #pragma unroll
      for (int mi = 0; mi < 4; ++mi){
        int row = wr*64 + mi*16 + l15;
        a[mi] = *(const short8v*)(&As[row*64 + (((s*4 + kslot) ^ (row&7))*8)]);
      }
      #pragma unroll
      for (int ni = 0; ni < 4; ++ni){
        int col = wc*64 + ni*16 + l15;
        b[ni] = *(const short8v*)(&Bs[col*64 + (((s*4 + kslot) ^ (col&7))*8)]);
      }
      #pragma unroll
      for (int mi = 0; mi < 4; ++mi)
        #pragma unroll
        for (int ni = 0; ni < 4; ++ni)
          acc[mi][ni] = __builtin_amdgcn_mfma_f32_16x16x32_bf16(a[mi], b[ni], acc[mi][ni], 0, 0, 0);
    }
    __syncthreads();
  }
  // C write: row=(lane>>4)*4+reg, col=lane&15 (m89/m91)
  #pragma unroll
  for (int mi = 0; mi < 4; ++mi){
    #pragma unroll
    for (int ni = 0; ni < 4; ++ni){
      int gcol = n0 + wc*64 + ni*16 + l15;
      if (gcol >= Nn) continue;
      #pragma unroll
      for (int r = 0; r < 4; ++r){
        int grow = m0 + wr*64 + mi*16 + kslot*4 + r;
        if (grow < M){
          size_t idx = (size_t)grow*Nn + gcol;
          if (BFOUT) ((u16*)Cv)[idx] = f2bf(acc[mi][ni][r]);
          else       ((float*)Cv)[idx] = acc[mi][ni][r];
        }
      }
    }
  }
  if (FUSE_ATT){
    int h = blockIdx.y;   // BN=128 == one head
    float asv[4], adv[4];
    #pragma unroll
    for (int ni = 0; ni < 4; ++ni){
      int c = wc*64 + ni*16 + l15;
      asv[ni] = a_s[h*128 + c];
      adv[ni] = a_d[h*128 + c];
    }
    #pragma unroll
    for (int mi = 0; mi < 4; ++mi){
      #pragma unroll
      for (int r = 0; r < 4; ++r){
        float ps = 0.f, pd = 0.f;
        #pragma unroll
        for (int ni = 0; ni < 4; ++ni){
          ps += acc[mi][ni][r]*asv[ni];
          pd += acc[mi][ni][r]*adv[ni];
        }
        #pragma unroll
        for (int m = 8; m >= 1; m >>= 1){ ps += __shfl_xor(ps,m); pd += __shfl_xor(pd,m); }
        int grow = m0 + wr*64 + mi*16 + kslot*4 + r;
        if (l15 == 0 && grow < M){
          // wc splits the head's 128 cols: partial sums -> combine via two halves
          atomicAdd(&ssrc[grow*4 + h], ps);
          atomicAdd(&sdst[grow*4 + h], pd);
        }
      }
    }
  }
}

// ---------------- legacy GEMM (BM=128, BN=64, BK=32) for layer 3 ----------------
__global__ __launch_bounds__(256) void k_gemm_bf16(const u16* __restrict__ A,
    const u16* __restrict__ Bt, float* __restrict__ C, int M, int K, int Nn){
  __shared__ __align__(16) u16 As[128*32];
  __shared__ __align__(16) u16 Bs[64*32];
  const int tid = threadIdx.x;
  const int wid = tid >> 6, lane = tid & 63;
  const int l15 = lane & 15, kslot = lane >> 4;
  const int m0 = blockIdx.x * 128, n0 = blockIdx.y * 64;
  f32x4 acc[2][4];
  #pragma unroll
  for (int mi = 0; mi < 2; ++mi)
    #pragma unroll
    for (int ni = 0; ni < 4; ++ni)
      acc[mi][ni] = (f32x4){0.f,0.f,0.f,0.f};
  for (int kt = 0; kt < K; kt += 32){
    #pragma unroll
    for (int i = 0; i < 2; ++i){
      int chunk = tid + i*256;
      int row = chunk >> 2, c16 = chunk & 3;
      uint4 v = make_uint4(0u,0u,0u,0u);
      int grow = m0 + row;
      if (grow < M) v = *(const uint4*)(A + (size_t)grow*K + kt + c16*8);
      *(uint4*)(&As[row*32 + ((c16*8) ^ ((row&3)<<3))]) = v;
    }
    {
      int row = tid >> 2, c16 = tid & 3;
      uint4 v = *(const uint4*)(Bt + (size_t)(n0+row)*K + kt + c16*8);
      *(uint4*)(&Bs[row*32 + ((c16*8) ^ ((row&3)<<3))]) = v;
    }
    __syncthreads();
    short8v a[2], b[4];
    #pragma unroll
    for (int mi = 0; mi < 2; ++mi){
      int r = wid*32 + mi*16 + l15;
      a[mi] = *(const short8v*)(&As[r*32 + ((kslot*8) ^ ((r&3)<<3))]);
    }
    #pragma unroll
    for (int ni = 0; ni < 4; ++ni){
      int c = ni*16 + l15;
      b[ni] = *(const short8v*)(&Bs[c*32 + ((kslot*8) ^ ((c&3)<<3))]);
    }
    #pragma unroll
    for (int mi = 0; mi < 2; ++mi)
      #pragma unroll
      for (int ni = 0; ni < 4; ++ni)
        acc[mi][ni] = __builtin_amdgcn_mfma_f32_16x16x32_bf16(a[mi], b[ni], acc[mi][ni], 0, 0, 0);
    __syncthreads();
  }
  #pragma unroll
  for (int mi = 0; mi < 2; ++mi)
    #pragma unroll
    for (int ni = 0; ni < 4; ++ni)
      #pragma unroll
      for (int r = 0; r < 4; ++r){
        int grow = m0 + wid*32 + mi*16 + kslot*4 + r;
        if (grow < M) C[(size_t)grow*Nn + n0 + ni*16 + l15] = acc[mi][ni][r];
      }
}

// ---------------- attention scalars ----------------
__global__ void k_ve(const float* __restrict__ We, const float* __restrict__ ae,
                     float* __restrict__ veall, int H, int C, int base){
  int t = blockIdx.x*blockDim.x + threadIdx.x;
  if (t >= 72*H) return;
  int k = t / H, h = t - k*H;
  const float* wrow = We + (size_t)k*H*C + (size_t)h*C;
  const float* arow = ae + (size_t)h*C;
  float s = 0.f;
  for (int c = 0; c < C; ++c) s += wrow[c]*arow[c];
  veall[k*9 + base + h] = s;
}

__global__ __launch_bounds__(256) void k_se_all(const float* __restrict__ attr,
    const float* __restrict__ veall, float* __restrict__ se){
  __shared__ float vel[72*9];
  for (int i = threadIdx.x; i < 72*9; i += blockDim.x) vel[i] = veall[i];
  __syncthreads();
  int e = blockIdx.x*blockDim.x + threadIdx.x;
  if (e >= NEDGES) return;
  const float4* row = (const float4*)(attr + (size_t)e*72);
  float s[9];
  #pragma unroll
  for (int j = 0; j < 9; ++j) s[j] = 0.f;
  #pragma unroll
  for (int kk = 0; kk < 18; ++kk){
    float4 a = row[kk];
    #pragma unroll
    for (int j = 0; j < 9; ++j)
      s[j] += a.x*vel[(kk*4+0)*9+j] + a.y*vel[(kk*4+1)*9+j]
            + a.z*vel[(kk*4+2)*9+j] + a.w*vel[(kk*4+3)*9+j];
  }
  #pragma unroll
  for (int j = 0; j < 9; ++j) se[(size_t)e*9+j] = s[j];
}

__global__ void k_seloop_all(const int* __restrict__ off, const int* __restrict__ csr_eid,
                             const float* __restrict__ se, float* __restrict__ seloop){
  int n = blockIdx.x*blockDim.x + threadIdx.x;
  if (n >= NNODES) return;
  int beg = off[n];
  int dr = off[n+1] - 1 - beg;
  float s[9];
  #pragma unroll
  for (int j = 0; j < 9; ++j) s[j] = 0.f;
  for (int p = beg; p < beg+dr; ++p){
    int eid = csr_eid[p];
    #pragma unroll
    for (int j = 0; j < 9; ++j) s[j] += se[(size_t)eid*9+j];
  }
  float inv = 1.0f / fmaxf((float)dr, 1.0f);
  #pragma unroll
  for (int j = 0; j < 9; ++j) seloop[(size_t)n*9+j] = s[j]*inv;
}

// H=1, C=64 (f32 xs3)
__global__ void k_satt64(const float* __restrict__ xs, const float* __restrict__ a_s,
                         const float* __restrict__ a_d,
                         float* __restrict__ ssrc, float* __restrict__ sdst){
  int wid = threadIdx.x >> 6, lane = threadIdx.x & 63;
  int n = blockIdx.x*4 + wid;
  if (n >= NNODES) return;
  float v = xs[(size_t)n*64 + lane];
  float ps = v*a_s[lane], pd = v*a_d[lane];
  for (int m = 32; m >= 1; m >>= 1){ ps += __shfl_xor(ps,m); pd += __shfl_xor(pd,m); }
  if (lane == 0){ ssrc[n] = ps; sdst[n] = pd; }
}

// ---------------- aggregation: layers 1&2 (H=4,C=128), bf16 in/out ----------------
__global__ __launch_bounds__(128) void k_agg12(const u16* __restrict__ xs,
    const int* __restrict__ off, const int* __restrict__ csr_src, const int* __restrict__ csr_eid,
    const float* __restrict__ ssrc, const float* __restrict__ sdst,
    const float* __restrict__ se, const float* __restrict__ seloop, int soff,
    const float* __restrict__ bias, u16* __restrict__ out){
  __shared__ float s_al[DEGCAP][4];
  __shared__ int s_col[DEGCAP];
  int n = blockIdx.x;
  int t = threadIdx.x;
  int beg = off[n];
  int deg = off[n+1] - beg;
  if (deg > DEGCAP) deg = DEGCAP;
  for (int base = 0; base < deg; base += 32){
    int e = base + (t>>2);
    int h = t & 3;
    if (e < deg){
      int col = csr_src[beg+e];
      int eid = csr_eid[beg+e];
      float s = ssrc[col*4+h] + sdst[n*4+h]
              + (eid < 0 ? seloop[(size_t)n*9+soff+h] : se[(size_t)eid*9+soff+h]);
      s = (s > 0.f) ? s : 0.2f*s;
      s_al[e][h] = s;
      if (h == 0) s_col[e] = col;
    }
  }
  __syncthreads();
  if (t < 4){
    float m = -1e30f;
    for (int e = 0; e < deg; ++e) m = fmaxf(m, s_al[e][t]);
    float z = 0.f;
    for (int e = 0; e < deg; ++e){ float ex = expf(s_al[e][t]-m); s_al[e][t] = ex; z += ex; }
    float inv = 1.0f/(z + 1e-16f);
    for (int e = 0; e < deg; ++e) s_al[e][t] *= inv;
  }
  __syncthreads();
  float4 acc = make_float4(0.f,0.f,0.f,0.f);
  int hh = t >> 5;
  for (int e = 0; e < deg; ++e){
    float a = s_al[e][hh];
    ushort4 v = ((const ushort4*)(xs + (size_t)s_col[e]*512))[t];
    acc.x += a*bf2f(v.x); acc.y += a*bf2f(v.y); acc.z += a*bf2f(v.z); acc.w += a*bf2f(v.w);
  }
  float4 b4 = ((const float4*)bias)[t];
  float ox = fmaxf(acc.x + b4.x, 0.f);
  float oy = fmaxf(acc.y + b4.y, 0.f);
  float oz = fmaxf(acc.z + b4.z, 0.f);
  float ow = fmaxf(acc.w + b4.w, 0.f);
  ((ushort4*)(out + (size_t)n*512))[t] = make_ushort4(f2bf(ox), f2bf(oy), f2bf(oz), f2bf(ow));
}

// ---------------- aggregation: layer 3 (H=1,C=64), f32 ----------------
__global__ __launch_bounds__(64) void k_agg3(const float* __restrict__ xs,
    const int* __restrict__ off, const int* __restrict__ csr_src, const int* __restrict__ csr_eid,
    const float* __restrict__ ssrc, const float* __restrict__ sdst,
    const float* __restrict__ se, const float* __restrict__ seloop,
    const float* __restrict__ bias, float* __restrict__ out){
  __shared__ float s_al[DEGCAP];
  __shared__ int s_col[DEGCAP];
  int n = blockIdx.x;
  int t = threadIdx.x;
  int beg = off[n];
  int deg = off[n+1] - beg;
  if (deg > DEGCAP) deg = DEGCAP;
  for (int base = 0; base < deg; base += 64){
    int e = base + t;
    if (e < deg){
      int col = csr_src[beg+e];
      int eid = csr_eid[beg+e];
      float s = ssrc[col] + sdst[n]
              + (eid < 0 ? seloop[(size_t)n*9+8] : se[(size_t)eid*9+8]);
      s = (s > 0.f) ? s : 0.2f*s;
      s_al[e] = s;
      s_col[e] = col;
    }
  }
  __syncthreads();
  if (t == 0){
    float m = -1e30f;
    for (int e = 0; e < deg; ++e) m = fmaxf(m, s_al[e]);
    float z = 0.f;
    for (int e = 0; e < deg; ++e){ float ex = expf(s_al[e]-m); s_al[e] = ex; z += ex; }
    float inv = 1.0f/(z + 1e-16f);
    for (int e = 0; e < deg; ++e) s_al[e] *= inv;
  }
  __syncthreads();
  float acc = 0.f;
  for (int e = 0; e < deg; ++e) acc += s_al[e] * xs[(size_t)s_col[e]*64 + t];
  out[(size_t)n*64 + t] = fmaxf(acc + bias[t], 0.f);
}

// ---------------- pooling (batch is sorted) ----------------
__global__ __launch_bounds__(64) void k_pool(const float* __restrict__ h, const int* __restrict__ batch,
                                             float* __restrict__ pooled, int* __restrict__ cntg){
  int l = threadIdx.x;
  int start = blockIdx.x * 256;
  if (start >= NNODES) return;
  int endn = min(start + 256, NNODES);
  float acc = 0.f;
  int curg = batch[start];
  int run = 0;
  for (int n = start; n < endn; ++n){
    int g = batch[n];
    if (g != curg){
      atomicAdd(&pooled[curg*64+l], acc);
      if (l == 0) atomicAdd(&cntg[curg], run);
      acc = 0.f; run = 0; curg = g;
    }
    acc += h[(size_t)n*64 + l];
    ++run;
  }
  atomicAdd(&pooled[curg*64+l], acc);
  if (l == 0) atomicAdd(&cntg[curg], run);
}

// ---------------- final FFN + softmax ----------------
__global__ void k_ffn(const float* __restrict__ pooled, const int* __restrict__ cntg,
                      const float* __restrict__ og,
                      const float* __restrict__ Wf1, const float* __restrict__ bf1,
                      const float* __restrict__ Wf2, const float* __restrict__ bf2,
                      float* __restrict__ out){
  __shared__ float z[135];
  __shared__ float z1[67];
  __shared__ float o2[2];
  int g = blockIdx.x, t = threadIdx.x;
  if (t < 64) z[t] = pooled[g*64+t] * (1.0f/fmaxf((float)cntg[g], 1.0f));
  else if (t < 135) z[t] = og[g*OGW + (t-64)];
  __syncthreads();
  if (t < 67){
    float s = bf1[t];
    for (int d = 0; d < 135; ++d) s += z[d]*Wf1[d*67+t];
    z1[t] = fmaxf(s, 0.f);
  }
  __syncthreads();
  if (t < 2){
    float s = bf2[t];
    for (int j = 0; j < 67; ++j) s += z1[j]*Wf2[j*2+t];
    o2[t] = s;
  }
  __syncthreads();
  if (t == 0){
    float m = fmaxf(o2[0], o2[1]);
    float e0 = expf(o2[0]-m), e1 = expf(o2[1]-m);
    float inv = 1.0f/(e0+e1);
    out[g*2+0] = e0*inv;
    out[g*2+1] = e1*inv;
  }
}

extern "C" void kernel_launch(void* const* d_in, const int* in_sizes, int n_in,
                              void* d_out, int out_size, void* d_ws, size_t ws_size,
                              hipStream_t stream){
  const float* x     = (const float*)d_in[0];
  const int*   ei    = (const int*)d_in[1];
  const float* eattr = (const float*)d_in[2];
  const int*   batch = (const int*)d_in[3];
  const float* W1  = (const float*)d_in[4];
  const float* We1 = (const float*)d_in[5];
  const float* as1 = (const float*)d_in[6];
  const float* ad1 = (const float*)d_in[7];
  const float* ae1 = (const float*)d_in[8];
  const float* b1  = (const float*)d_in[9];
  const float* W2  = (const float*)d_in[10];
  const float* We2 = (const float*)d_in[11];
  const float* as2 = (const float*)d_in[12];
  const float* ad2 = (const float*)d_in[13];
  const float* ae2 = (const float*)d_in[14];
  const float* b2  = (const float*)d_in[15];
  const float* W3  = (const float*)d_in[16];
  const float* We3 = (const float*)d_in[17];
  const float* as3 = (const float*)d_in[18];
  const float* ad3 = (const float*)d_in[19];
  const float* ae3 = (const float*)d_in[20];
  const float* b3  = (const float*)d_in[21];
  const float* Wf1 = (const float*)d_in[22];
  const float* bf1 = (const float*)d_in[23];
  const float* Wf2 = (const float*)d_in[24];
  const float* bf2 = (const float*)d_in[25];
  (void)in_sizes; (void)n_in; (void)out_size; (void)ws_size;
  const int* src = ei;
  const int* dst = ei + NEDGES;
  float* out = (float*)d_out;

  char* base = (char*)d_ws;
  size_t woff = 0;
  auto alloc = [&](size_t bytes)->char*{
    char* p = base + woff;
    woff += (bytes + 255) & ~(size_t)255;
    return p;
  };
  u16*   xsb    = (u16*)  alloc((size_t)NNODES*512*2);
  u16*   hb     = (u16*)  alloc((size_t)NNODES*512*2);
  float* xs3    = (float*)alloc((size_t)NNODES*64*4);
  float* h3     = (float*)alloc((size_t)NNODES*64*4);
  u16*   xb     = (u16*)  alloc((size_t)NNODES*64*2);
  u16*   Wt1    = (u16*)  alloc((size_t)64*512*2);
  u16*   Wt2    = (u16*)  alloc((size_t)512*512*2);
  u16*   Wt3    = (u16*)  alloc((size_t)512*64*2);
  float* se     = (float*)alloc((size_t)NEDGES*9*4);
  float* seloop = (float*)alloc((size_t)NNODES*9*4);
  float* ssrc   = (float*)alloc((size_t)NNODES*4*4);
  float* sdst   = (float*)alloc((size_t)NNODES*4*4);
  float* veall  = (float*)alloc(72*9*4);
  int*   gb     = (int*)alloc((size_t)NEDGES*4);
  int*   deg    = (int*)alloc((size_t)NNODES*4);
  int*   cnt    = (int*)alloc((size_t)NNODES*4);
  int*   csroff = (int*)alloc((size_t)(NNODES+1)*4);
  int*   csrsrc = (int*)alloc((size_t)NEA*4);
  int*   csreid = (int*)alloc((size_t)NEA*4);
  int*   gcnt   = (int*)alloc(NG*4);
  int*   goff   = (int*)alloc(NG*4);
  int*   gcur   = (int*)alloc(NG*4);
  int*   sortedeid = (int*)alloc((size_t)NEDGES*4);
  float* og     = (float*)alloc((size_t)NG*OGW*4);
  float* pooled = (float*)alloc((size_t)NG*64*4);
  int*   cntg   = (int*)alloc((size_t)NG*4);

  hipMemsetAsync(deg,    0, (size_t)NNODES*4, stream);
  hipMemsetAsync(cnt,    0, (size_t)NNODES*4, stream);
  hipMemsetAsync(gcnt,   0, NG*4, stream);
  hipMemsetAsync(og,     0, (size_t)NG*OGW*4, stream);
  hipMemsetAsync(pooled, 0, (size_t)NG*64*4, stream);
  hipMemsetAsync(cntg,   0, (size_t)NG*4, stream);
  hipMemsetAsync(ssrc,   0, (size_t)NNODES*4*4, stream);
  hipMemsetAsync(sdst,   0, (size_t)NNODES*4*4, stream);

  // casts
  k_cast4 <<<ceil_div(NNODES*64/4,256),256,0,stream>>>(x, xb, NNODES*64/4);
  k_castWt<<<ceil_div(64*512,256),256,0,stream>>>(W1, Wt1, 64, 512);
  k_castWt<<<ceil_div(512*512,256),256,0,stream>>>(W2, Wt2, 512, 512);
  k_castWt<<<ceil_div(512*64,256),256,0,stream>>>(W3, Wt3, 512, 64);

  // CSR build
  k_deg <<<ceil_div(NEDGES,256),256,0,stream>>>(dst, deg);
  k_scan<<<1,1024,0,stream>>>(deg, csroff);
  k_fill<<<ceil_div(NEDGES,256),256,0,stream>>>(src, dst, csroff, cnt, csrsrc, csreid);
  k_self<<<ceil_div(NNODES,256),256,0,stream>>>(csroff, csrsrc, csreid);

  // 1-gram: counting sort by graph + register segment sum
  k_gb_hist <<<ceil_div(NEDGES,256),256,0,stream>>>(src, batch, gb, gcnt);
  k_gscan   <<<1,NG,0,stream>>>(gcnt, goff, gcur);
  k_gscatter<<<ceil_div(NEDGES,256),256,0,stream>>>(gb, gcur, sortedeid);
  k_og2     <<<NG*8,256,0,stream>>>(eattr, goff, gcnt, sortedeid, og);
  k_ognorm  <<<1,128,0,stream>>>(og);

  // edge scores for all 3 layers in one eattr pass
  k_ve<<<2,256,0,stream>>>(We1, ae1, veall, 4, 128, 0);
  k_ve<<<2,256,0,stream>>>(We2, ae2, veall, 4, 128, 4);
  k_ve<<<1,128,0,stream>>>(We3, ae3, veall, 1, 64, 8);
  k_se_all    <<<ceil_div(NEDGES,256),256,0,stream>>>(eattr, veall, se);
  k_seloop_all<<<ceil_div(NNODES,256),256,0,stream>>>(csroff, csreid, se, seloop);

  dim3 g128(ceil_div(NNODES,128), 4);

  // ---- layer 1 (satt fused into GEMM epilogue) ----
  k_gemm128<true,true><<<g128,256,0,stream>>>(xb, Wt1, xsb, NNODES, 64, 512, as1, ad1, ssrc, sdst);
  k_agg12<<<NNODES,128,0,stream>>>(xsb, csroff, csrsrc, csreid, ssrc, sdst, se, seloop, 0, b1, hb);

  // ---- layer 2 ----
  hipMemsetAsync(ssrc, 0, (size_t)NNODES*4*4, stream);
  hipMemsetAsync(sdst, 0, (size_t)NNODES*4*4, stream);
  k_gemm128<true,true><<<g128,256,0,stream>>>(hb, Wt2, xsb, NNODES, 512, 512, as2, ad2, ssrc, sdst);
  k_agg12<<<NNODES,128,0,stream>>>(xsb, csroff, csrsrc, csreid, ssrc, sdst, se, seloop, 4, b2, hb);

  // ---- layer 3 (H=1, C=64) ----
  k_gemm_bf16<<<dim3(ceil_div(NNODES,128),1),256,0,stream>>>(hb, Wt3, xs3, NNODES, 512, 64);
  k_satt64<<<ceil_div(NNODES,4),256,0,stream>>>(xs3, as3, ad3, ssrc, sdst);
  k_agg3  <<<NNODES,64,0,stream>>>(xs3, csroff, csrsrc, csreid, ssrc, sdst, se, seloop, b3, h3);

  // ---- pool + FFN + softmax ----
  k_pool<<<ceil_div(NNODES,256),64,0,stream>>>(h3, batch, pooled, cntg);
  k_ffn <<<NG,192,0,stream>>>(pooled, cntg, og, Wf1, bf1, Wf2, bf2, out);
}

// Round 5
// 771.111 us; speedup vs baseline: 2.5496x; 1.1368x over previous
//
#include <hip/hip_runtime.h>

#define NNODES 50000
#define NEDGES 400000
#define NEA    450000
#define NG     128
#define DEGCAP 96
#define OGW    72

typedef unsigned short u16;
typedef unsigned int   u32;
typedef __attribute__((ext_vector_type(8))) short short8v;
typedef __attribute__((ext_vector_type(4))) float f32x4;

static inline int ceil_div(int a, int b){ return (a + b - 1)/b; }

__device__ __forceinline__ u16 f2bf(float f){
  u32 u = __builtin_bit_cast(u32, f);
  u = (u + 0x7fffu + ((u >> 16) & 1u)) >> 16;   // RNE
  return (u16)u;
}
__device__ __forceinline__ float bf2f(u16 b){
  return __builtin_bit_cast(float, (u32)b << 16);
}
__device__ __forceinline__ void gload_lds16(const u16* g, u16* l){
  __builtin_amdgcn_global_load_lds((const __attribute__((address_space(1))) void*)g,
                                   (__attribute__((address_space(3))) void*)l, 16, 0, 0);
}

// ---------------- fused casts: xb, Wt1, Wt2, Wt3 ----------------
__global__ void k_prep(const float* __restrict__ x, u16* __restrict__ xb,
                       const float* __restrict__ W1, u16* __restrict__ Wt1,
                       const float* __restrict__ W2, u16* __restrict__ Wt2,
                       const float* __restrict__ W3, u16* __restrict__ Wt3){
  int i = blockIdx.x*blockDim.x + threadIdx.x;
  if (i < 800000){  // x: 3.2M floats as float4
    float4 v = ((const float4*)x)[i];
    ((ushort4*)xb)[i] = make_ushort4(f2bf(v.x), f2bf(v.y), f2bf(v.z), f2bf(v.w));
    return;
  }
  i -= 800000;
  if (i < 32768){   // Wt1 [512][64] <- W1 [64][512]
    int n = i >> 6, k = i & 63;
    Wt1[i] = f2bf(W1[(size_t)k*512 + n]);
    return;
  }
  i -= 32768;
  if (i < 262144){  // Wt2 [512][512] <- W2
    int n = i >> 9, k = i & 511;
    Wt2[i] = f2bf(W2[(size_t)k*512 + n]);
    return;
  }
  i -= 262144;
  if (i < 32768){   // Wt3 [64][512] <- W3 [512][64]
    int n = i >> 9, k = i & 511;
    Wt3[i] = f2bf(W3[(size_t)k*64 + n]);
  }
}

// ---------------- CSR build ----------------
__global__ void k_deg(const int* __restrict__ dst, int* __restrict__ deg){
  int e = blockIdx.x*blockDim.x + threadIdx.x;
  if (e < NEDGES) atomicAdd(&deg[dst[e]], 1);
}

__global__ __launch_bounds__(1024) void k_scan(const int* __restrict__ deg, int* __restrict__ off){
  __shared__ int s[1024];
  const int CH = (NNODES + 1023)/1024;
  int t = threadIdx.x;
  int i0 = t*CH, i1 = min(i0 + CH, NNODES);
  int loc = 0;
  for (int i = i0; i < i1; ++i) loc += deg[i] + 1;
  s[t] = loc; __syncthreads();
  for (int o = 1; o < 1024; o <<= 1){
    int v = (t >= o) ? s[t-o] : 0;
    __syncthreads();
    s[t] += v;
    __syncthreads();
  }
  int excl = s[t] - loc;
  for (int i = i0; i < i1; ++i){ off[i] = excl; excl += deg[i] + 1; }
  if (t == 1023) off[NNODES] = s[1023];
}

__global__ void k_fill(const int* __restrict__ src, const int* __restrict__ dst,
                       const int* __restrict__ off, int* __restrict__ cnt,
                       int* __restrict__ csr_src, int* __restrict__ csr_eid){
  int e = blockIdx.x*blockDim.x + threadIdx.x;
  if (e >= NEDGES) return;
  int d = dst[e];
  int p = off[d] + atomicAdd(&cnt[d], 1);
  csr_src[p] = src[e];
  csr_eid[p] = e;
}

__global__ void k_self(const int* __restrict__ off, int* __restrict__ csr_src, int* __restrict__ csr_eid){
  int n = blockIdx.x*blockDim.x + threadIdx.x;
  if (n >= NNODES) return;
  int p = off[n+1] - 1;
  csr_src[p] = n;
  csr_eid[p] = -1;
}

// ---------------- og: counting sort by graph + register segment-sum ----------------
__global__ void k_gb_hist(const int* __restrict__ src, const int* __restrict__ batch,
                          int* __restrict__ gb, int* __restrict__ gcnt){
  __shared__ int h[NG];
  int t = threadIdx.x;
  if (t < NG) h[t] = 0;
  __syncthreads();
  int e = blockIdx.x*blockDim.x + t;
  if (e < NEDGES){
    int g = batch[src[e]];
    gb[e] = g;
    atomicAdd(&h[g], 1);
  }
  __syncthreads();
  if (t < NG && h[t]) atomicAdd(&gcnt[t], h[t]);
}

__global__ void k_gscan(const int* __restrict__ gcnt, int* __restrict__ goff, int* __restrict__ gcur){
  __shared__ int s[NG];
  int t = threadIdx.x;
  int v = gcnt[t];
  s[t] = v; __syncthreads();
  for (int o = 1; o < NG; o <<= 1){
    int x = (t >= o) ? s[t-o] : 0;
    __syncthreads();
    s[t] += x;
    __syncthreads();
  }
  goff[t] = s[t] - v;
  gcur[t] = s[t] - v;
}

__global__ void k_gscatter(const int* __restrict__ gb, int* __restrict__ gcur,
                           int* __restrict__ sortedeid){
  __shared__ int lcnt[NG];
  __shared__ int lbase[NG];
  int t = threadIdx.x;
  if (t < NG) lcnt[t] = 0;
  __syncthreads();
  int e = blockIdx.x*blockDim.x + t;
  int g = -1, lr = 0;
  if (e < NEDGES){
    g = gb[e];
    lr = atomicAdd(&lcnt[g], 1);
  }
  __syncthreads();
  if (t < NG && lcnt[t]) lbase[t] = atomicAdd(&gcur[t], lcnt[t]);
  __syncthreads();
  if (e < NEDGES) sortedeid[lbase[g] + lr] = e;
}

__global__ __launch_bounds__(256) void k_og2(const float* __restrict__ attr,
    const int* __restrict__ goff, const int* __restrict__ gcnt,
    const int* __restrict__ sortedeid, float* __restrict__ og){
  __shared__ float red[4][OGW];
  int g = blockIdx.x >> 3, chunk = blockIdx.x & 7;
  int lane = threadIdx.x & 63, w = threadIdx.x >> 6;
  int beg = goff[g], cnt = gcnt[g];
  int cbeg = beg + ((cnt*chunk) >> 3);
  int cend = beg + ((cnt*(chunk+1)) >> 3);
  float acc0 = 0.f, acc1 = 0.f;
  for (int i = cbeg + w*4; i < cend; i += 16){
    int n4 = min(4, cend - i);
    int eids[4];
    #pragma unroll
    for (int u = 0; u < 4; ++u) eids[u] = (u < n4) ? sortedeid[i+u] : -1;
    #pragma unroll
    for (int u = 0; u < 4; ++u){
      if (eids[u] >= 0){
        acc0 += attr[(size_t)eids[u]*72 + lane];
        if (lane < 7) acc1 += attr[(size_t)eids[u]*72 + 64 + lane];
      }
    }
  }
  red[w][lane] = acc0;
  if (lane < 7) red[w][64+lane] = acc1;
  else if (lane == 63) red[w][71] = 0.f;
  __syncthreads();
  int t = threadIdx.x;
  if (t < 71){
    float s = red[0][t] + red[1][t] + red[2][t] + red[3][t];
    if (s != 0.f) atomicAdd(&og[g*OGW + t], s);
  }
}

// ---------------- gemm128: BM=BN=128, BK=64, gload_lds, fused att, LDS-staged C ----------------
// A bf16 [M,K]; Bt bf16 [Nn=512,K]; C bf16 [M,512]. blockIdx.x = N-tile(=head), blockIdx.y = M-tile.
__global__ __launch_bounds__(256) void k_gemm128(const u16* __restrict__ A,
    const u16* __restrict__ Bt, u16* __restrict__ C, int M, int K,
    const float* __restrict__ a_s, const float* __restrict__ a_d,
    float* __restrict__ ssrc, float* __restrict__ sdst){
  __shared__ __align__(16) u16 smem[128*128];   // As = [0,8192), Bs = [8192,16384); reused for C-stage
  u16* As = smem;
  u16* Bs = smem + 128*64;
  __shared__ float s_ps[128][2];
  __shared__ float s_pd[128][2];
  const int tid = threadIdx.x;
  const int wid = tid >> 6, lane = tid & 63;
  const int l15 = lane & 15, kslot = lane >> 4;
  const int wr = wid >> 1, wc = wid & 1;
  const int h = blockIdx.x;               // N-tile == head
  const int m0 = blockIdx.y * 128, n0 = h * 128;
  const int Nn = 512;
  f32x4 acc[4][4];
  #pragma unroll
  for (int mi = 0; mi < 4; ++mi)
    #pragma unroll
    for (int ni = 0; ni < 4; ++ni)
      acc[mi][ni] = (f32x4){0.f,0.f,0.f,0.f};

  for (int kt = 0; kt < K; kt += 64){
    #pragma unroll
    for (int r = 0; r < 4; ++r){
      int chunk = (r*4 + wid)*64 + lane;
      int row = chunk >> 3, c8 = chunk & 7;
      int srcc = c8 ^ (row & 7);
      int grow = m0 + row; if (grow > M-1) grow = M-1;
      gload_lds16(A + (size_t)grow*K + kt + srcc*8, &As[chunk*8]);
    }
    #pragma unroll
    for (int r = 0; r < 4; ++r){
      int chunk = (r*4 + wid)*64 + lane;
      int row = chunk >> 3, c8 = chunk & 7;
      int srcc = c8 ^ (row & 7);
      gload_lds16(Bt + (size_t)(n0+row)*K + kt + srcc*8, &Bs[chunk*8]);
    }
    __syncthreads();
    #pragma unroll
    for (int s = 0; s < 2; ++s){
      short8v a[4], b[4];
      #pragma unroll
      for (int mi = 0; mi < 4; ++mi){
        int row = wr*64 + mi*16 + l15;
        a[mi] = *(const short8v*)(&As[row*64 + (((s*4 + kslot) ^ (row&7))*8)]);
      }
      #pragma unroll
      for (int ni = 0; ni < 4; ++ni){
        int col = wc*64 + ni*16 + l15;
        b[ni] = *(const short8v*)(&Bs[col*64 + (((s*4 + kslot) ^ (col&7))*8)]);
      }
      #pragma unroll
      for (int mi = 0; mi < 4; ++mi)
        #pragma unroll
        for (int ni = 0; ni < 4; ++ni)
          acc[mi][ni] = __builtin_amdgcn_mfma_f32_16x16x32_bf16(a[mi], b[ni], acc[mi][ni], 0, 0, 0);
    }
    __syncthreads();
  }
  // stage C tile (bf16) into smem + att partials (C/D layout: col=lane&15, row=(lane>>4)*4+reg)
  float asv[4], adv[4];
  #pragma unroll
  for (int ni = 0; ni < 4; ++ni){
    int c = wc*64 + ni*16 + l15;
    asv[ni] = a_s[h*128 + c];
    adv[ni] = a_d[h*128 + c];
  }
  #pragma unroll
  for (int mi = 0; mi < 4; ++mi){
    #pragma unroll
    for (int r = 0; r < 4; ++r){
      int row_l = wr*64 + mi*16 + kslot*4 + r;
      float ps = 0.f, pd = 0.f;
      #pragma unroll
      for (int ni = 0; ni < 4; ++ni){
        float v = acc[mi][ni][r];
        smem[row_l*128 + wc*64 + ni*16 + l15] = f2bf(v);
        ps += v*asv[ni];
        pd += v*adv[ni];
      }
      #pragma unroll
      for (int m = 8; m >= 1; m >>= 1){ ps += __shfl_xor(ps,m); pd += __shfl_xor(pd,m); }
      if (l15 == 0){ s_ps[row_l][wc] = ps; s_pd[row_l][wc] = pd; }
    }
  }
  __syncthreads();
  // coalesced copy-out: 2048 chunks of 16B
  #pragma unroll
  for (int i = 0; i < 8; ++i){
    int c = i*256 + tid;
    int row = c >> 4, c16 = c & 15;
    int grow = m0 + row;
    if (grow < M)
      *(uint4*)(C + (size_t)grow*Nn + n0 + c16*8) = *(const uint4*)(&smem[row*128 + c16*8]);
  }
  if (tid < 128){
    int grow = m0 + tid;
    if (grow < M){
      ssrc[grow*4 + h] = s_ps[tid][0] + s_ps[tid][1];
      sdst[grow*4 + h] = s_pd[tid][0] + s_pd[tid][1];
    }
  }
}

// ---------------- gemm64: layer 3, BM=64, BN=64, BK=64, K=512, f32 out ----------------
__global__ __launch_bounds__(256) void k_gemm64(const u16* __restrict__ A,
    const u16* __restrict__ Bt, float* __restrict__ C, int M){
  __shared__ __align__(16) u16 As[64*64];
  __shared__ __align__(16) u16 Bs[64*64];
  const int tid = threadIdx.x;
  const int wid = tid >> 6, lane = tid & 63;
  const int l15 = lane & 15, kslot = lane >> 4;
  const int m0 = blockIdx.x * 64;
  f32x4 acc[4];
  #pragma unroll
  for (int ni = 0; ni < 4; ++ni) acc[ni] = (f32x4){0.f,0.f,0.f,0.f};
  for (int kt = 0; kt < 512; kt += 64){
    #pragma unroll
    for (int r = 0; r < 2; ++r){
      int chunk = r*256 + tid;
      int row = chunk >> 3, c8 = chunk & 7;
      int srcc = c8 ^ (row & 7);
      int grow = m0 + row; if (grow > M-1) grow = M-1;
      gload_lds16(A + (size_t)grow*512 + kt + srcc*8, &As[chunk*8]);
    }
    #pragma unroll
    for (int r = 0; r < 2; ++r){
      int chunk = r*256 + tid;
      int row = chunk >> 3, c8 = chunk & 7;
      int srcc = c8 ^ (row & 7);
      gload_lds16(Bt + (size_t)row*512 + kt + srcc*8, &Bs[chunk*8]);
    }
    __syncthreads();
    #pragma unroll
    for (int s = 0; s < 2; ++s){
      int row = wid*16 + l15;
      short8v a = *(const short8v*)(&As[row*64 + (((s*4 + kslot) ^ (row&7))*8)]);
      #pragma unroll
      for (int ni = 0; ni < 4; ++ni){
        int col = ni*16 + l15;
        short8v b = *(const short8v*)(&Bs[col*64 + (((s*4 + kslot) ^ (col&7))*8)]);
        acc[ni] = __builtin_amdgcn_mfma_f32_16x16x32_bf16(a, b, acc[ni], 0, 0, 0);
      }
    }
    __syncthreads();
  }
  #pragma unroll
  for (int ni = 0; ni < 4; ++ni)
    #pragma unroll
    for (int r = 0; r < 4; ++r){
      int grow = m0 + wid*16 + kslot*4 + r;
      if (grow < M) C[(size_t)grow*64 + ni*16 + l15] = acc[ni][r];
    }
}

// ---------------- attention ve (all 3 layers, one block) ----------------
// veall [k=0..71][9]: 0-3 layer1, 4-7 layer2, 8 layer3
__global__ __launch_bounds__(1024) void k_ve_all(const float* __restrict__ We1, const float* __restrict__ ae1,
                         const float* __restrict__ We2, const float* __restrict__ ae2,
                         const float* __restrict__ We3, const float* __restrict__ ae3,
                         float* __restrict__ veall){
  int t = threadIdx.x;
  const float* We; const float* ae; int H, C, base, li;
  if (t < 288){ We = We1; ae = ae1; H = 4; C = 128; base = 0; li = t; }
  else if (t < 576){ We = We2; ae = ae2; H = 4; C = 128; base = 4; li = t - 288; }
  else if (t < 648){ We = We3; ae = ae3; H = 1; C = 64; base = 8; li = t - 576; }
  else return;
  int k = li / H, h = li - k*H;
  const float* wrow = We + (size_t)k*H*C + (size_t)h*C;
  const float* arow = ae + (size_t)h*C;
  float s = 0.f;
  for (int c = 0; c < C; ++c) s += wrow[c]*arow[c];
  veall[k*9 + base + h] = s;
}

__global__ __launch_bounds__(256) void k_se_all(const float* __restrict__ attr,
    const float* __restrict__ veall, float* __restrict__ se){
  __shared__ float vel[72*9];
  for (int i = threadIdx.x; i < 72*9; i += blockDim.x) vel[i] = veall[i];
  __syncthreads();
  int e = blockIdx.x*blockDim.x + threadIdx.x;
  if (e >= NEDGES) return;
  const float4* row = (const float4*)(attr + (size_t)e*72);
  float s[9];
  #pragma unroll
  for (int j = 0; j < 9; ++j) s[j] = 0.f;
  #pragma unroll
  for (int kk = 0; kk < 18; ++kk){
    float4 a = row[kk];
    #pragma unroll
    for (int j = 0; j < 9; ++j)
      s[j] += a.x*vel[(kk*4+0)*9+j] + a.y*vel[(kk*4+1)*9+j]
            + a.z*vel[(kk*4+2)*9+j] + a.w*vel[(kk*4+3)*9+j];
  }
  #pragma unroll
  for (int j = 0; j < 9; ++j) se[(size_t)e*9+j] = s[j];
}

__global__ void k_seloop_all(const int* __restrict__ off, const int* __restrict__ csr_eid,
                             const float* __restrict__ se, float* __restrict__ seloop){
  int n = blockIdx.x*blockDim.x + threadIdx.x;
  if (n >= NNODES) return;
  int beg = off[n];
  int dr = off[n+1] - 1 - beg;
  float s[9];
  #pragma unroll
  for (int j = 0; j < 9; ++j) s[j] = 0.f;
  for (int p = beg; p < beg+dr; ++p){
    int eid = csr_eid[p];
    #pragma unroll
    for (int j = 0; j < 9; ++j) s[j] += se[(size_t)eid*9+j];
  }
  float inv = 1.0f / fmaxf((float)dr, 1.0f);
  #pragma unroll
  for (int j = 0; j < 9; ++j) seloop[(size_t)n*9+j] = s[j]*inv;
}

// H=1, C=64 (f32 xs3)
__global__ void k_satt64(const float* __restrict__ xs, const float* __restrict__ a_s,
                         const float* __restrict__ a_d,
                         float* __restrict__ ssrc, float* __restrict__ sdst){
  int wid = threadIdx.x >> 6, lane = threadIdx.x & 63;
  int n = blockIdx.x*4 + wid;
  if (n >= NNODES) return;
  float v = xs[(size_t)n*64 + lane];
  float ps = v*a_s[lane], pd = v*a_d[lane];
  for (int m = 32; m >= 1; m >>= 1){ ps += __shfl_xor(ps,m); pd += __shfl_xor(pd,m); }
  if (lane == 0){ ssrc[n] = ps; sdst[n] = pd; }
}

// ---------------- aggregation: layers 1&2 ----------------
__global__ __launch_bounds__(128) void k_agg12(const u16* __restrict__ xs,
    const int* __restrict__ off, const int* __restrict__ csr_src, const int* __restrict__ csr_eid,
    const float* __restrict__ ssrc, const float* __restrict__ sdst,
    const float* __restrict__ se, const float* __restrict__ seloop, int soff,
    const float* __restrict__ bias, u16* __restrict__ out){
  __shared__ float s_al[DEGCAP][4];
  __shared__ int s_col[DEGCAP];
  int n = blockIdx.x;
  int t = threadIdx.x;
  int beg = off[n];
  int deg = off[n+1] - beg;
  if (deg > DEGCAP) deg = DEGCAP;
  for (int base = 0; base < deg; base += 32){
    int e = base + (t>>2);
    int h = t & 3;
    if (e < deg){
      int col = csr_src[beg+e];
      int eid = csr_eid[beg+e];
      float s = ssrc[col*4+h] + sdst[n*4+h]
              + (eid < 0 ? seloop[(size_t)n*9+soff+h] : se[(size_t)eid*9+soff+h]);
      s = (s > 0.f) ? s : 0.2f*s;
      s_al[e][h] = s;
      if (h == 0) s_col[e] = col;
    }
  }
  __syncthreads();
  if (t < 4){
    float m = -1e30f;
    for (int e = 0; e < deg; ++e) m = fmaxf(m, s_al[e][t]);
    float z = 0.f;
    for (int e = 0; e < deg; ++e){ float ex = expf(s_al[e][t]-m); s_al[e][t] = ex; z += ex; }
    float inv = 1.0f/(z + 1e-16f);
    for (int e = 0; e < deg; ++e) s_al[e][t] *= inv;
  }
  __syncthreads();
  float4 acc = make_float4(0.f,0.f,0.f,0.f);
  int hh = t >> 5;
  for (int e = 0; e < deg; ++e){
    float a = s_al[e][hh];
    ushort4 v = ((const ushort4*)(xs + (size_t)s_col[e]*512))[t];
    acc.x += a*bf2f(v.x); acc.y += a*bf2f(v.y); acc.z += a*bf2f(v.z); acc.w += a*bf2f(v.w);
  }
  float4 b4 = ((const float4*)bias)[t];
  float ox = fmaxf(acc.x + b4.x, 0.f);
  float oy = fmaxf(acc.y + b4.y, 0.f);
  float oz = fmaxf(acc.z + b4.z, 0.f);
  float ow = fmaxf(acc.w + b4.w, 0.f);
  ((ushort4*)(out + (size_t)n*512))[t] = make_ushort4(f2bf(ox), f2bf(oy), f2bf(oz), f2bf(ow));
}

// ---------------- aggregation: layer 3 ----------------
__global__ __launch_bounds__(64) void k_agg3(const float* __restrict__ xs,
    const int* __restrict__ off, const int* __restrict__ csr_src, const int* __restrict__ csr_eid,
    const float* __restrict__ ssrc, const float* __restrict__ sdst,
    const float* __restrict__ se, const float* __restrict__ seloop,
    const float* __restrict__ bias, float* __restrict__ out){
  __shared__ float s_al[DEGCAP];
  __shared__ int s_col[DEGCAP];
  int n = blockIdx.x;
  int t = threadIdx.x;
  int beg = off[n];
  int deg = off[n+1] - beg;
  if (deg > DEGCAP) deg = DEGCAP;
  for (int base = 0; base < deg; base += 64){
    int e = base + t;
    if (e < deg){
      int col = csr_src[beg+e];
      int eid = csr_eid[beg+e];
      float s = ssrc[col] + sdst[n]
              + (eid < 0 ? seloop[(size_t)n*9+8] : se[(size_t)eid*9+8]);
      s = (s > 0.f) ? s : 0.2f*s;
      s_al[e] = s;
      s_col[e] = col;
    }
  }
  __syncthreads();
  if (t == 0){
    float m = -1e30f;
    for (int e = 0; e < deg; ++e) m = fmaxf(m, s_al[e]);
    float z = 0.f;
    for (int e = 0; e < deg; ++e){ float ex = expf(s_al[e]-m); s_al[e] = ex; z += ex; }
    float inv = 1.0f/(z + 1e-16f);
    for (int e = 0; e < deg; ++e) s_al[e] *= inv;
  }
  __syncthreads();
  float acc = 0.f;
  for (int e = 0; e < deg; ++e) acc += s_al[e] * xs[(size_t)s_col[e]*64 + t];
  out[(size_t)n*64 + t] = fmaxf(acc + bias[t], 0.f);
}

// ---------------- pooling ----------------
__global__ __launch_bounds__(64) void k_pool(const float* __restrict__ h, const int* __restrict__ batch,
                                             float* __restrict__ pooled, int* __restrict__ cntg){
  int l = threadIdx.x;
  int start = blockIdx.x * 256;
  if (start >= NNODES) return;
  int endn = min(start + 256, NNODES);
  float acc = 0.f;
  int curg = batch[start];
  int run = 0;
  for (int n = start; n < endn; ++n){
    int g = batch[n];
    if (g != curg){
      atomicAdd(&pooled[curg*64+l], acc);
      if (l == 0) atomicAdd(&cntg[curg], run);
      acc = 0.f; run = 0; curg = g;
    }
    acc += h[(size_t)n*64 + l];
    ++run;
  }
  atomicAdd(&pooled[curg*64+l], acc);
  if (l == 0) atomicAdd(&cntg[curg], run);
}

// ---------------- final FFN + softmax (og normalized inline) ----------------
__global__ void k_ffn(const float* __restrict__ pooled, const int* __restrict__ cntg,
                      const float* __restrict__ og,
                      const float* __restrict__ Wf1, const float* __restrict__ bf1,
                      const float* __restrict__ Wf2, const float* __restrict__ bf2,
                      float* __restrict__ out){
  __shared__ float z[135];
  __shared__ float z1[67];
  __shared__ float o2[2];
  int g = blockIdx.x, t = threadIdx.x;
  if (t < 64) z[t] = pooled[g*64+t] * (1.0f/fmaxf((float)cntg[g], 1.0f));
  else if (t < 135) z[t] = og[g*OGW + (t-64)];
  __syncthreads();
  if (t == 0){
    float s = 0.f;
    for (int k = 0; k < 71; ++k) s += z[64+k]*z[64+k];
    float scale = 1.0f / fmaxf(sqrtf(s), 1e-12f);
    for (int k = 0; k < 71; ++k) z[64+k] *= scale;
  }
  __syncthreads();
  if (t < 67){
    float s = bf1[t];
    for (int d = 0; d < 135; ++d) s += z[d]*Wf1[d*67+t];
    z1[t] = fmaxf(s, 0.f);
  }
  __syncthreads();
  if (t < 2){
    float s = bf2[t];
    for (int j = 0; j < 67; ++j) s += z1[j]*Wf2[j*2+t];
    o2[t] = s;
  }
  __syncthreads();
  if (t == 0){
    float m = fmaxf(o2[0], o2[1]);
    float e0 = expf(o2[0]-m), e1 = expf(o2[1]-m);
    float inv = 1.0f/(e0+e1);
    out[g*2+0] = e0*inv;
    out[g*2+1] = e1*inv;
  }
}

extern "C" void kernel_launch(void* const* d_in, const int* in_sizes, int n_in,
                              void* d_out, int out_size, void* d_ws, size_t ws_size,
                              hipStream_t stream){
  const float* x     = (const float*)d_in[0];
  const int*   ei    = (const int*)d_in[1];
  const float* eattr = (const float*)d_in[2];
  const int*   batch = (const int*)d_in[3];
  const float* W1  = (const float*)d_in[4];
  const float* We1 = (const float*)d_in[5];
  const float* as1 = (const float*)d_in[6];
  const float* ad1 = (const float*)d_in[7];
  const float* ae1 = (const float*)d_in[8];
  const float* b1  = (const float*)d_in[9];
  const float* W2  = (const float*)d_in[10];
  const float* We2 = (const float*)d_in[11];
  const float* as2 = (const float*)d_in[12];
  const float* ad2 = (const float*)d_in[13];
  const float* ae2 = (const float*)d_in[14];
  const float* b2  = (const float*)d_in[15];
  const float* W3  = (const float*)d_in[16];
  const float* We3 = (const float*)d_in[17];
  const float* as3 = (const float*)d_in[18];
  const float* ad3 = (const float*)d_in[19];
  const float* ae3 = (const float*)d_in[20];
  const float* b3  = (const float*)d_in[21];
  const float* Wf1 = (const float*)d_in[22];
  const float* bf1 = (const float*)d_in[23];
  const float* Wf2 = (const float*)d_in[24];
  const float* bf2 = (const float*)d_in[25];
  (void)in_sizes; (void)n_in; (void)out_size; (void)ws_size;
  const int* src = ei;
  const int* dst = ei + NEDGES;
  float* out = (float*)d_out;

  char* base = (char*)d_ws;
  size_t woff = 0;
  auto alloc = [&](size_t bytes)->char*{
    char* p = base + woff;
    woff += (bytes + 255) & ~(size_t)255;
    return p;
  };
  u16*   xsb    = (u16*)  alloc((size_t)NNODES*512*2);
  u16*   hb     = (u16*)  alloc((size_t)NNODES*512*2);
  float* xs3    = (float*)alloc((size_t)NNODES*64*4);
  float* h3     = (float*)alloc((size_t)NNODES*64*4);
  u16*   xb     = (u16*)  alloc((size_t)NNODES*64*2);
  u16*   Wt1    = (u16*)  alloc((size_t)512*64*2);
  u16*   Wt2    = (u16*)  alloc((size_t)512*512*2);
  u16*   Wt3    = (u16*)  alloc((size_t)64*512*2);
  float* se     = (float*)alloc((size_t)NEDGES*9*4);
  float* seloop = (float*)alloc((size_t)NNODES*9*4);
  float* ssrc   = (float*)alloc((size_t)NNODES*4*4);
  float* sdst   = (float*)alloc((size_t)NNODES*4*4);
  float* veall  = (float*)alloc(72*9*4);
  int*   gb     = (int*)alloc((size_t)NEDGES*4);
  int*   csroff = (int*)alloc((size_t)(NNODES+1)*4);
  int*   csrsrc = (int*)alloc((size_t)NEA*4);
  int*   csreid = (int*)alloc((size_t)NEA*4);
  int*   goff   = (int*)alloc(NG*4);
  int*   gcur   = (int*)alloc(NG*4);
  int*   sortedeid = (int*)alloc((size_t)NEDGES*4);
  // ---- zero-initialized region (single memset) ----
  size_t z0 = woff;
  int*   deg    = (int*)alloc((size_t)NNODES*4);
  int*   cnt    = (int*)alloc((size_t)NNODES*4);
  int*   gcnt   = (int*)alloc(NG*4);
  float* og     = (float*)alloc((size_t)NG*OGW*4);
  float* pooled = (float*)alloc((size_t)NG*64*4);
  int*   cntg   = (int*)alloc((size_t)NG*4);
  size_t zlen = woff - z0;

  hipMemsetAsync(base + z0, 0, zlen, stream);

  // fused casts
  k_prep<<<ceil_div(800000+32768+262144+32768,256),256,0,stream>>>(x, xb, W1, Wt1, W2, Wt2, W3, Wt3);

  // CSR build
  k_deg <<<ceil_div(NEDGES,256),256,0,stream>>>(dst, deg);
  k_scan<<<1,1024,0,stream>>>(deg, csroff);
  k_fill<<<ceil_div(NEDGES,256),256,0,stream>>>(src, dst, csroff, cnt, csrsrc, csreid);
  k_self<<<ceil_div(NNODES,256),256,0,stream>>>(csroff, csrsrc, csreid);

  // 1-gram
  k_gb_hist <<<ceil_div(NEDGES,256),256,0,stream>>>(src, batch, gb, gcnt);
  k_gscan   <<<1,NG,0,stream>>>(gcnt, goff, gcur);
  k_gscatter<<<ceil_div(NEDGES,256),256,0,stream>>>(gb, gcur, sortedeid);
  k_og2     <<<NG*8,256,0,stream>>>(eattr, goff, gcnt, sortedeid, og);

  // edge scores for all 3 layers
  k_ve_all    <<<1,704,0,stream>>>(We1, ae1, We2, ae2, We3, ae3, veall);
  k_se_all    <<<ceil_div(NEDGES,256),256,0,stream>>>(eattr, veall, se);
  k_seloop_all<<<ceil_div(NNODES,256),256,0,stream>>>(csroff, csreid, se, seloop);

  dim3 g128(4, ceil_div(NNODES,128));   // N-tile fastest: A panel reused by 4 consecutive blocks

  // ---- layer 1 ----
  k_gemm128<<<g128,256,0,stream>>>(xb, Wt1, xsb, NNODES, 64, as1, ad1, ssrc, sdst);
  k_agg12<<<NNODES,128,0,stream>>>(xsb, csroff, csrsrc, csreid, ssrc, sdst, se, seloop, 0, b1, hb);

  // ---- layer 2 ----
  k_gemm128<<<g128,256,0,stream>>>(hb, Wt2, xsb, NNODES, 512, as2, ad2, ssrc, sdst);
  k_agg12<<<NNODES,128,0,stream>>>(xsb, csroff, csrsrc, csreid, ssrc, sdst, se, seloop, 4, b2, hb);

  // ---- layer 3 ----
  k_gemm64<<<ceil_div(NNODES,64),256,0,stream>>>(hb, Wt3, xs3, NNODES);
  k_satt64<<<ceil_div(NNODES,4),256,0,stream>>>(xs3, as3, ad3, ssrc, sdst);
  k_agg3  <<<NNODES,64,0,stream>>>(xs3, csroff, csrsrc, csreid, ssrc, sdst, se, seloop, b3, h3);

  // ---- pool + FFN ----
  k_pool<<<ceil_div(NNODES,256),64,0,stream>>>(h3, batch, pooled, cntg);
  k_ffn <<<NG,192,0,stream>>>(pooled, cntg, og, Wf1, bf1, Wf2, bf2, out);
}

// Round 6
// 687.525 us; speedup vs baseline: 2.8595x; 1.1216x over previous
//
#include <hip/hip_runtime.h>

#define NNODES 50000
#define NEDGES 400000
#define NEA    450000
#define NG     128
#define DEGCAP 96
#define OGW    72

typedef unsigned short u16;
typedef unsigned int   u32;
typedef __attribute__((ext_vector_type(8))) short short8v;
typedef __attribute__((ext_vector_type(4))) float f32x4;

static inline int ceil_div(int a, int b){ return (a + b - 1)/b; }

__device__ __forceinline__ u16 f2bf(float f){
  u32 u = __builtin_bit_cast(u32, f);
  u = (u + 0x7fffu + ((u >> 16) & 1u)) >> 16;   // RNE
  return (u16)u;
}
__device__ __forceinline__ float bf2f(u16 b){
  return __builtin_bit_cast(float, (u32)b << 16);
}
__device__ __forceinline__ void gload_lds16(const u16* g, u16* l){
  __builtin_amdgcn_global_load_lds((const __attribute__((address_space(1))) void*)g,
                                   (__attribute__((address_space(3))) void*)l, 16, 0, 0);
}

// ---------------- fused casts: xb, Wt1, Wt2, Wt3 ----------------
__global__ void k_prep(const float* __restrict__ x, u16* __restrict__ xb,
                       const float* __restrict__ W1, u16* __restrict__ Wt1,
                       const float* __restrict__ W2, u16* __restrict__ Wt2,
                       const float* __restrict__ W3, u16* __restrict__ Wt3){
  int i = blockIdx.x*blockDim.x + threadIdx.x;
  if (i < 800000){  // x: 3.2M floats as float4
    float4 v = ((const float4*)x)[i];
    ((ushort4*)xb)[i] = make_ushort4(f2bf(v.x), f2bf(v.y), f2bf(v.z), f2bf(v.w));
    return;
  }
  i -= 800000;
  if (i < 32768){   // Wt1 [512][64] <- W1 [64][512]
    int n = i >> 6, k = i & 63;
    Wt1[i] = f2bf(W1[(size_t)k*512 + n]);
    return;
  }
  i -= 32768;
  if (i < 262144){  // Wt2 [512][512] <- W2
    int n = i >> 9, k = i & 511;
    Wt2[i] = f2bf(W2[(size_t)k*512 + n]);
    return;
  }
  i -= 262144;
  if (i < 32768){   // Wt3 [64][512] <- W3 [512][64]
    int n = i >> 9, k = i & 511;
    Wt3[i] = f2bf(W3[(size_t)k*64 + n]);
  }
}

// ---------------- CSR build (deg fused with gb/gcnt histogram) ----------------
__global__ void k_deg_gb(const int* __restrict__ src, const int* __restrict__ dst,
                         const int* __restrict__ batch,
                         int* __restrict__ deg, int* __restrict__ gb, int* __restrict__ gcnt){
  __shared__ int h[NG];
  int t = threadIdx.x;
  if (t < NG) h[t] = 0;
  __syncthreads();
  int e = blockIdx.x*blockDim.x + t;
  if (e < NEDGES){
    atomicAdd(&deg[dst[e]], 1);
    int g = batch[src[e]];
    gb[e] = g;
    atomicAdd(&h[g], 1);
  }
  __syncthreads();
  if (t < NG && h[t]) atomicAdd(&gcnt[t], h[t]);
}

__global__ __launch_bounds__(1024) void k_scan(const int* __restrict__ deg, int* __restrict__ off){
  __shared__ int s[1024];
  const int CH = (NNODES + 1023)/1024;
  int t = threadIdx.x;
  int i0 = t*CH, i1 = min(i0 + CH, NNODES);
  int loc = 0;
  for (int i = i0; i < i1; ++i) loc += deg[i] + 1;
  s[t] = loc; __syncthreads();
  for (int o = 1; o < 1024; o <<= 1){
    int v = (t >= o) ? s[t-o] : 0;
    __syncthreads();
    s[t] += v;
    __syncthreads();
  }
  int excl = s[t] - loc;
  for (int i = i0; i < i1; ++i){ off[i] = excl; excl += deg[i] + 1; }
  if (t == 1023) off[NNODES] = s[1023];
}

__global__ void k_fill(const int* __restrict__ src, const int* __restrict__ dst,
                       const int* __restrict__ off, int* __restrict__ cnt,
                       int* __restrict__ csr_src, int* __restrict__ csr_eid){
  int e = blockIdx.x*blockDim.x + threadIdx.x;
  if (e >= NEDGES) return;
  int d = dst[e];
  int p = off[d] + atomicAdd(&cnt[d], 1);
  csr_src[p] = src[e];
  csr_eid[p] = e;
}

__global__ void k_self(const int* __restrict__ off, int* __restrict__ csr_src, int* __restrict__ csr_eid){
  int n = blockIdx.x*blockDim.x + threadIdx.x;
  if (n >= NNODES) return;
  int p = off[n+1] - 1;
  csr_src[p] = n;
  csr_eid[p] = -1;
}

// ---------------- og: counting sort by graph ----------------
__global__ void k_gscan(const int* __restrict__ gcnt, int* __restrict__ goff, int* __restrict__ gcur){
  __shared__ int s[NG];
  int t = threadIdx.x;
  int v = gcnt[t];
  s[t] = v; __syncthreads();
  for (int o = 1; o < NG; o <<= 1){
    int x = (t >= o) ? s[t-o] : 0;
    __syncthreads();
    s[t] += x;
    __syncthreads();
  }
  goff[t] = s[t] - v;
  gcur[t] = s[t] - v;
}

__global__ void k_gscatter(const int* __restrict__ gb, int* __restrict__ gcur,
                           int* __restrict__ sortedeid){
  __shared__ int lcnt[NG];
  __shared__ int lbase[NG];
  int t = threadIdx.x;
  if (t < NG) lcnt[t] = 0;
  __syncthreads();
  int e = blockIdx.x*blockDim.x + t;
  int g = -1, lr = 0;
  if (e < NEDGES){
    g = gb[e];
    lr = atomicAdd(&lcnt[g], 1);
  }
  __syncthreads();
  if (t < NG && lcnt[t]) lbase[t] = atomicAdd(&gcur[t], lcnt[t]);
  __syncthreads();
  if (e < NEDGES) sortedeid[lbase[g] + lr] = e;
}

// og2 v3: float4 gather, register acc, conflict-free LDS reduce.
// grid = NG*16; block 256. Lane layout: esub=lane>>4 (edge slot), l16=lane&15 (col group).
__global__ __launch_bounds__(256) void k_og2(const float* __restrict__ attr,
    const int* __restrict__ goff, const int* __restrict__ gcnt,
    const int* __restrict__ sortedeid, float* __restrict__ og){
  __shared__ float red[16][OGW];
  int g = blockIdx.x >> 4, chunk = blockIdx.x & 15;
  int lane = threadIdx.x & 63, w = threadIdx.x >> 6;
  int esub = lane >> 4, l16 = lane & 15;
  int slot = w*4 + esub;
  int beg = goff[g], cnt = gcnt[g];
  int cbeg = beg + ((cnt*chunk) >> 4);
  int cend = beg + ((cnt*(chunk+1)) >> 4);
  f32x4 acc  = {0.f,0.f,0.f,0.f};
  f32x4 acch = {0.f,0.f,0.f,0.f};
  for (int i0 = cbeg; i0 < cend; i0 += 32){
    int e1 = i0 + slot, e2 = i0 + 16 + slot;
    int id1 = (e1 < cend) ? sortedeid[e1] : -1;
    int id2 = (e2 < cend) ? sortedeid[e2] : -1;
    f32x4 v1 = {0.f,0.f,0.f,0.f}, v2 = {0.f,0.f,0.f,0.f};
    f32x4 h1 = {0.f,0.f,0.f,0.f}, h2 = {0.f,0.f,0.f,0.f};
    if (id1 >= 0){
      v1 = *(const f32x4*)(attr + (size_t)id1*72 + l16*4);
      if (l16 < 2) h1 = *(const f32x4*)(attr + (size_t)id1*72 + 64 + l16*4);
    }
    if (id2 >= 0){
      v2 = *(const f32x4*)(attr + (size_t)id2*72 + l16*4);
      if (l16 < 2) h2 = *(const f32x4*)(attr + (size_t)id2*72 + 64 + l16*4);
    }
    acc += v1; acc += v2;
    if (l16 < 2){ acch += h1; acch += h2; }
  }
  // conflict-free per-slot store (all 72 cols of each slot written)
  #pragma unroll
  for (int j = 0; j < 4; ++j) red[slot][l16*4 + j] = acc[j];
  if (l16 < 2){
    #pragma unroll
    for (int j = 0; j < 4; ++j) red[slot][64 + l16*4 + j] = acch[j];
  }
  __syncthreads();
  int t = threadIdx.x;
  if (t < 71){
    float s = 0.f;
    #pragma unroll
    for (int q = 0; q < 16; ++q) s += red[q][t];
    atomicAdd(&og[g*OGW + t], s);
  }
}

// ---------------- gemm128: BM=BN=128, BK=64, gload_lds, fused att, LDS-staged C ----------------
__global__ __launch_bounds__(256) void k_gemm128(const u16* __restrict__ A,
    const u16* __restrict__ Bt, u16* __restrict__ C, int M, int K,
    const float* __restrict__ a_s, const float* __restrict__ a_d,
    float* __restrict__ ssrc, float* __restrict__ sdst){
  __shared__ __align__(16) u16 smem[128*128];
  u16* As = smem;
  u16* Bs = smem + 128*64;
  __shared__ float s_ps[128][2];
  __shared__ float s_pd[128][2];
  const int tid = threadIdx.x;
  const int wid = tid >> 6, lane = tid & 63;
  const int l15 = lane & 15, kslot = lane >> 4;
  const int wr = wid >> 1, wc = wid & 1;
  const int h = blockIdx.x;
  const int m0 = blockIdx.y * 128, n0 = h * 128;
  const int Nn = 512;
  f32x4 acc[4][4];
  #pragma unroll
  for (int mi = 0; mi < 4; ++mi)
    #pragma unroll
    for (int ni = 0; ni < 4; ++ni)
      acc[mi][ni] = (f32x4){0.f,0.f,0.f,0.f};

  for (int kt = 0; kt < K; kt += 64){
    #pragma unroll
    for (int r = 0; r < 4; ++r){
      int chunk = (r*4 + wid)*64 + lane;
      int row = chunk >> 3, c8 = chunk & 7;
      int srcc = c8 ^ (row & 7);
      int grow = m0 + row; if (grow > M-1) grow = M-1;
      gload_lds16(A + (size_t)grow*K + kt + srcc*8, &As[chunk*8]);
    }
    #pragma unroll
    for (int r = 0; r < 4; ++r){
      int chunk = (r*4 + wid)*64 + lane;
      int row = chunk >> 3, c8 = chunk & 7;
      int srcc = c8 ^ (row & 7);
      gload_lds16(Bt + (size_t)(n0+row)*K + kt + srcc*8, &Bs[chunk*8]);
    }
    __syncthreads();
    #pragma unroll
    for (int s = 0; s < 2; ++s){
      short8v a[4], b[4];
      #pragma unroll
      for (int mi = 0; mi < 4; ++mi){
        int row = wr*64 + mi*16 + l15;
        a[mi] = *(const short8v*)(&As[row*64 + (((s*4 + kslot) ^ (row&7))*8)]);
      }
      #pragma unroll
      for (int ni = 0; ni < 4; ++ni){
        int col = wc*64 + ni*16 + l15;
        b[ni] = *(const short8v*)(&Bs[col*64 + (((s*4 + kslot) ^ (col&7))*8)]);
      }
      #pragma unroll
      for (int mi = 0; mi < 4; ++mi)
        #pragma unroll
        for (int ni = 0; ni < 4; ++ni)
          acc[mi][ni] = __builtin_amdgcn_mfma_f32_16x16x32_bf16(a[mi], b[ni], acc[mi][ni], 0, 0, 0);
    }
    __syncthreads();
  }
  float asv[4], adv[4];
  #pragma unroll
  for (int ni = 0; ni < 4; ++ni){
    int c = wc*64 + ni*16 + l15;
    asv[ni] = a_s[h*128 + c];
    adv[ni] = a_d[h*128 + c];
  }
  #pragma unroll
  for (int mi = 0; mi < 4; ++mi){
    #pragma unroll
    for (int r = 0; r < 4; ++r){
      int row_l = wr*64 + mi*16 + kslot*4 + r;
      float ps = 0.f, pd = 0.f;
      #pragma unroll
      for (int ni = 0; ni < 4; ++ni){
        float v = acc[mi][ni][r];
        smem[row_l*128 + wc*64 + ni*16 + l15] = f2bf(v);
        ps += v*asv[ni];
        pd += v*adv[ni];
      }
      #pragma unroll
      for (int m = 8; m >= 1; m >>= 1){ ps += __shfl_xor(ps,m); pd += __shfl_xor(pd,m); }
      if (l15 == 0){ s_ps[row_l][wc] = ps; s_pd[row_l][wc] = pd; }
    }
  }
  __syncthreads();
  #pragma unroll
  for (int i = 0; i < 8; ++i){
    int c = i*256 + tid;
    int row = c >> 4, c16 = c & 15;
    int grow = m0 + row;
    if (grow < M)
      *(uint4*)(C + (size_t)grow*Nn + n0 + c16*8) = *(const uint4*)(&smem[row*128 + c16*8]);
  }
  if (tid < 128){
    int grow = m0 + tid;
    if (grow < M){
      ssrc[grow*4 + h] = s_ps[tid][0] + s_ps[tid][1];
      sdst[grow*4 + h] = s_pd[tid][0] + s_pd[tid][1];
    }
  }
}

// ---------------- gemm64: layer 3, BM=64, BN=64, BK=64, K=512, f32 out ----------------
__global__ __launch_bounds__(256) void k_gemm64(const u16* __restrict__ A,
    const u16* __restrict__ Bt, float* __restrict__ C, int M){
  __shared__ __align__(16) u16 As[64*64];
  __shared__ __align__(16) u16 Bs[64*64];
  const int tid = threadIdx.x;
  const int wid = tid >> 6, lane = tid & 63;
  const int l15 = lane & 15, kslot = lane >> 4;
  const int m0 = blockIdx.x * 64;
  f32x4 acc[4];
  #pragma unroll
  for (int ni = 0; ni < 4; ++ni) acc[ni] = (f32x4){0.f,0.f,0.f,0.f};
  for (int kt = 0; kt < 512; kt += 64){
    #pragma unroll
    for (int r = 0; r < 2; ++r){
      int chunk = r*256 + tid;
      int row = chunk >> 3, c8 = chunk & 7;
      int srcc = c8 ^ (row & 7);
      int grow = m0 + row; if (grow > M-1) grow = M-1;
      gload_lds16(A + (size_t)grow*512 + kt + srcc*8, &As[chunk*8]);
    }
    #pragma unroll
    for (int r = 0; r < 2; ++r){
      int chunk = r*256 + tid;
      int row = chunk >> 3, c8 = chunk & 7;
      int srcc = c8 ^ (row & 7);
      gload_lds16(Bt + (size_t)row*512 + kt + srcc*8, &Bs[chunk*8]);
    }
    __syncthreads();
    #pragma unroll
    for (int s = 0; s < 2; ++s){
      int row = wid*16 + l15;
      short8v a = *(const short8v*)(&As[row*64 + (((s*4 + kslot) ^ (row&7))*8)]);
      #pragma unroll
      for (int ni = 0; ni < 4; ++ni){
        int col = ni*16 + l15;
        short8v b = *(const short8v*)(&Bs[col*64 + (((s*4 + kslot) ^ (col&7))*8)]);
        acc[ni] = __builtin_amdgcn_mfma_f32_16x16x32_bf16(a, b, acc[ni], 0, 0, 0);
      }
    }
    __syncthreads();
  }
  #pragma unroll
  for (int ni = 0; ni < 4; ++ni)
    #pragma unroll
    for (int r = 0; r < 4; ++r){
      int grow = m0 + wid*16 + kslot*4 + r;
      if (grow < M) C[(size_t)grow*64 + ni*16 + l15] = acc[ni][r];
    }
}

// ---------------- attention ve (all 3 layers, one block) ----------------
__global__ __launch_bounds__(1024) void k_ve_all(const float* __restrict__ We1, const float* __restrict__ ae1,
                         const float* __restrict__ We2, const float* __restrict__ ae2,
                         const float* __restrict__ We3, const float* __restrict__ ae3,
                         float* __restrict__ veall){
  int t = threadIdx.x;
  const float* We; const float* ae; int H, C, base, li;
  if (t < 288){ We = We1; ae = ae1; H = 4; C = 128; base = 0; li = t; }
  else if (t < 576){ We = We2; ae = ae2; H = 4; C = 128; base = 4; li = t - 288; }
  else if (t < 648){ We = We3; ae = ae3; H = 1; C = 64; base = 8; li = t - 576; }
  else return;
  int k = li / H, h = li - k*H;
  const float* wrow = We + (size_t)k*H*C + (size_t)h*C;
  const float* arow = ae + (size_t)h*C;
  float s = 0.f;
  for (int c = 0; c < C; ++c) s += wrow[c]*arow[c];
  veall[k*9 + base + h] = s;
}

__global__ __launch_bounds__(256) void k_se_all(const float* __restrict__ attr,
    const float* __restrict__ veall, float* __restrict__ se){
  __shared__ float vel[72*9];
  for (int i = threadIdx.x; i < 72*9; i += blockDim.x) vel[i] = veall[i];
  __syncthreads();
  int e = blockIdx.x*blockDim.x + threadIdx.x;
  if (e >= NEDGES) return;
  const float4* row = (const float4*)(attr + (size_t)e*72);
  float s[9];
  #pragma unroll
  for (int j = 0; j < 9; ++j) s[j] = 0.f;
  #pragma unroll
  for (int kk = 0; kk < 18; ++kk){
    float4 a = row[kk];
    #pragma unroll
    for (int j = 0; j < 9; ++j)
      s[j] += a.x*vel[(kk*4+0)*9+j] + a.y*vel[(kk*4+1)*9+j]
            + a.z*vel[(kk*4+2)*9+j] + a.w*vel[(kk*4+3)*9+j];
  }
  #pragma unroll
  for (int j = 0; j < 9; ++j) se[(size_t)e*9+j] = s[j];
}

__global__ void k_seloop_all(const int* __restrict__ off, const int* __restrict__ csr_eid,
                             const float* __restrict__ se, float* __restrict__ seloop){
  int n = blockIdx.x*blockDim.x + threadIdx.x;
  if (n >= NNODES) return;
  int beg = off[n];
  int dr = off[n+1] - 1 - beg;
  float s[9];
  #pragma unroll
  for (int j = 0; j < 9; ++j) s[j] = 0.f;
  for (int p = beg; p < beg+dr; ++p){
    int eid = csr_eid[p];
    #pragma unroll
    for (int j = 0; j < 9; ++j) s[j] += se[(size_t)eid*9+j];
  }
  float inv = 1.0f / fmaxf((float)dr, 1.0f);
  #pragma unroll
  for (int j = 0; j < 9; ++j) seloop[(size_t)n*9+j] = s[j]*inv;
}

// H=1, C=64 (f32 xs3)
__global__ void k_satt64(const float* __restrict__ xs, const float* __restrict__ a_s,
                         const float* __restrict__ a_d,
                         float* __restrict__ ssrc, float* __restrict__ sdst){
  int wid = threadIdx.x >> 6, lane = threadIdx.x & 63;
  int n = blockIdx.x*4 + wid;
  if (n >= NNODES) return;
  float v = xs[(size_t)n*64 + lane];
  float ps = v*a_s[lane], pd = v*a_d[lane];
  for (int m = 32; m >= 1; m >>= 1){ ps += __shfl_xor(ps,m); pd += __shfl_xor(pd,m); }
  if (lane == 0){ ssrc[n] = ps; sdst[n] = pd; }
}

// ---------------- aggregation: layers 1&2 (software-pipelined gather) ----------------
__global__ __launch_bounds__(128) void k_agg12(const u16* __restrict__ xs,
    const int* __restrict__ off, const int* __restrict__ csr_src, const int* __restrict__ csr_eid,
    const float* __restrict__ ssrc, const float* __restrict__ sdst,
    const float* __restrict__ se, const float* __restrict__ seloop, int soff,
    const float* __restrict__ bias, u16* __restrict__ out){
  __shared__ float s_al[DEGCAP][4];
  __shared__ int s_col[DEGCAP];
  int n = blockIdx.x;
  int t = threadIdx.x;
  int beg = off[n];
  int deg = off[n+1] - beg;
  if (deg > DEGCAP) deg = DEGCAP;
  for (int base = 0; base < deg; base += 32){
    int e = base + (t>>2);
    int h = t & 3;
    if (e < deg){
      int col = csr_src[beg+e];
      int eid = csr_eid[beg+e];
      float s = ssrc[col*4+h] + sdst[n*4+h]
              + (eid < 0 ? seloop[(size_t)n*9+soff+h] : se[(size_t)eid*9+soff+h]);
      s = (s > 0.f) ? s : 0.2f*s;
      s_al[e][h] = s;
      if (h == 0) s_col[e] = col;
    }
  }
  __syncthreads();
  if (t < 4){
    float m = -1e30f;
    for (int e = 0; e < deg; ++e) m = fmaxf(m, s_al[e][t]);
    float z = 0.f;
    for (int e = 0; e < deg; ++e){ float ex = expf(s_al[e][t]-m); s_al[e][t] = ex; z += ex; }
    float inv = 1.0f/(z + 1e-16f);
    for (int e = 0; e < deg; ++e) s_al[e][t] *= inv;
  }
  __syncthreads();
  float4 acc = make_float4(0.f,0.f,0.f,0.f);
  int hh = t >> 5;
  ushort4 v = ((const ushort4*)(xs + (size_t)s_col[0]*512))[t];   // deg >= 1 (self loop)
  for (int e = 0; e < deg; ++e){
    ushort4 vn = make_ushort4(0,0,0,0);
    if (e+1 < deg) vn = ((const ushort4*)(xs + (size_t)s_col[e+1]*512))[t];
    float a = s_al[e][hh];
    acc.x += a*bf2f(v.x); acc.y += a*bf2f(v.y); acc.z += a*bf2f(v.z); acc.w += a*bf2f(v.w);
    v = vn;
  }
  float4 b4 = ((const float4*)bias)[t];
  float ox = fmaxf(acc.x + b4.x, 0.f);
  float oy = fmaxf(acc.y + b4.y, 0.f);
  float oz = fmaxf(acc.z + b4.z, 0.f);
  float ow = fmaxf(acc.w + b4.w, 0.f);
  ((ushort4*)(out + (size_t)n*512))[t] = make_ushort4(f2bf(ox), f2bf(oy), f2bf(oz), f2bf(ow));
}

// ---------------- aggregation: layer 3 ----------------
__global__ __launch_bounds__(64) void k_agg3(const float* __restrict__ xs,
    const int* __restrict__ off, const int* __restrict__ csr_src, const int* __restrict__ csr_eid,
    const float* __restrict__ ssrc, const float* __restrict__ sdst,
    const float* __restrict__ se, const float* __restrict__ seloop,
    const float* __restrict__ bias, float* __restrict__ out){
  __shared__ float s_al[DEGCAP];
  __shared__ int s_col[DEGCAP];
  int n = blockIdx.x;
  int t = threadIdx.x;
  int beg = off[n];
  int deg = off[n+1] - beg;
  if (deg > DEGCAP) deg = DEGCAP;
  for (int base = 0; base < deg; base += 64){
    int e = base + t;
    if (e < deg){
      int col = csr_src[beg+e];
      int eid = csr_eid[beg+e];
      float s = ssrc[col] + sdst[n]
              + (eid < 0 ? seloop[(size_t)n*9+8] : se[(size_t)eid*9+8]);
      s = (s > 0.f) ? s : 0.2f*s;
      s_al[e] = s;
      s_col[e] = col;
    }
  }
  __syncthreads();
  if (t == 0){
    float m = -1e30f;
    for (int e = 0; e < deg; ++e) m = fmaxf(m, s_al[e]);
    float z = 0.f;
    for (int e = 0; e < deg; ++e){ float ex = expf(s_al[e]-m); s_al[e] = ex; z += ex; }
    float inv = 1.0f/(z + 1e-16f);
    for (int e = 0; e < deg; ++e) s_al[e] *= inv;
  }
  __syncthreads();
  float acc = 0.f;
  float v = xs[(size_t)s_col[0]*64 + t];
  for (int e = 0; e < deg; ++e){
    float vn = 0.f;
    if (e+1 < deg) vn = xs[(size_t)s_col[e+1]*64 + t];
    acc += s_al[e] * v;
    v = vn;
  }
  out[(size_t)n*64 + t] = fmaxf(acc + bias[t], 0.f);
}

// ---------------- pooling (batch sorted); 128 nodes per block ----------------
__global__ __launch_bounds__(64) void k_pool(const float* __restrict__ h, const int* __restrict__ batch,
                                             float* __restrict__ pooled, int* __restrict__ cntg){
  int l = threadIdx.x;
  int start = blockIdx.x * 128;
  if (start >= NNODES) return;
  int endn = min(start + 128, NNODES);
  float acc = 0.f;
  int curg = batch[start];
  int run = 0;
  for (int n = start; n < endn; ++n){
    int g = batch[n];
    if (g != curg){
      atomicAdd(&pooled[curg*64+l], acc);
      if (l == 0) atomicAdd(&cntg[curg], run);
      acc = 0.f; run = 0; curg = g;
    }
    acc += h[(size_t)n*64 + l];
    ++run;
  }
  atomicAdd(&pooled[curg*64+l], acc);
  if (l == 0) atomicAdd(&cntg[curg], run);
}

// ---------------- final FFN + softmax (og normalized inline) ----------------
__global__ void k_ffn(const float* __restrict__ pooled, const int* __restrict__ cntg,
                      const float* __restrict__ og,
                      const float* __restrict__ Wf1, const float* __restrict__ bf1,
                      const float* __restrict__ Wf2, const float* __restrict__ bf2,
                      float* __restrict__ out){
  __shared__ float z[135];
  __shared__ float z1[67];
  __shared__ float o2[2];
  int g = blockIdx.x, t = threadIdx.x;
  if (t < 64) z[t] = pooled[g*64+t] * (1.0f/fmaxf((float)cntg[g], 1.0f));
  else if (t < 135) z[t] = og[g*OGW + (t-64)];
  __syncthreads();
  if (t == 0){
    float s = 0.f;
    for (int k = 0; k < 71; ++k) s += z[64+k]*z[64+k];
    float scale = 1.0f / fmaxf(sqrtf(s), 1e-12f);
    for (int k = 0; k < 71; ++k) z[64+k] *= scale;
  }
  __syncthreads();
  if (t < 67){
    float s = bf1[t];
    for (int d = 0; d < 135; ++d) s += z[d]*Wf1[d*67+t];
    z1[t] = fmaxf(s, 0.f);
  }
  __syncthreads();
  if (t < 2){
    float s = bf2[t];
    for (int j = 0; j < 67; ++j) s += z1[j]*Wf2[j*2+t];
    o2[t] = s;
  }
  __syncthreads();
  if (t == 0){
    float m = fmaxf(o2[0], o2[1]);
    float e0 = expf(o2[0]-m), e1 = expf(o2[1]-m);
    float inv = 1.0f/(e0+e1);
    out[g*2+0] = e0*inv;
    out[g*2+1] = e1*inv;
  }
}

extern "C" void kernel_launch(void* const* d_in, const int* in_sizes, int n_in,
                              void* d_out, int out_size, void* d_ws, size_t ws_size,
                              hipStream_t stream){
  const float* x     = (const float*)d_in[0];
  const int*   ei    = (const int*)d_in[1];
  const float* eattr = (const float*)d_in[2];
  const int*   batch = (const int*)d_in[3];
  const float* W1  = (const float*)d_in[4];
  const float* We1 = (const float*)d_in[5];
  const float* as1 = (const float*)d_in[6];
  const float* ad1 = (const float*)d_in[7];
  const float* ae1 = (const float*)d_in[8];
  const float* b1  = (const float*)d_in[9];
  const float* W2  = (const float*)d_in[10];
  const float* We2 = (const float*)d_in[11];
  const float* as2 = (const float*)d_in[12];
  const float* ad2 = (const float*)d_in[13];
  const float* ae2 = (const float*)d_in[14];
  const float* b2  = (const float*)d_in[15];
  const float* W3  = (const float*)d_in[16];
  const float* We3 = (const float*)d_in[17];
  const float* as3 = (const float*)d_in[18];
  const float* ad3 = (const float*)d_in[19];
  const float* ae3 = (const float*)d_in[20];
  const float* b3  = (const float*)d_in[21];
  const float* Wf1 = (const float*)d_in[22];
  const float* bf1 = (const float*)d_in[23];
  const float* Wf2 = (const float*)d_in[24];
  const float* bf2 = (const float*)d_in[25];
  (void)in_sizes; (void)n_in; (void)out_size; (void)ws_size;
  const int* src = ei;
  const int* dst = ei + NEDGES;
  float* out = (float*)d_out;

  char* base = (char*)d_ws;
  size_t woff = 0;
  auto alloc = [&](size_t bytes)->char*{
    char* p = base + woff;
    woff += (bytes + 255) & ~(size_t)255;
    return p;
  };
  u16*   xsb    = (u16*)  alloc((size_t)NNODES*512*2);
  u16*   hb     = (u16*)  alloc((size_t)NNODES*512*2);
  float* xs3    = (float*)alloc((size_t)NNODES*64*4);
  float* h3     = (float*)alloc((size_t)NNODES*64*4);
  u16*   xb     = (u16*)  alloc((size_t)NNODES*64*2);
  u16*   Wt1    = (u16*)  alloc((size_t)512*64*2);
  u16*   Wt2    = (u16*)  alloc((size_t)512*512*2);
  u16*   Wt3    = (u16*)  alloc((size_t)64*512*2);
  float* se     = (float*)alloc((size_t)NEDGES*9*4);
  float* seloop = (float*)alloc((size_t)NNODES*9*4);
  float* ssrc   = (float*)alloc((size_t)NNODES*4*4);
  float* sdst   = (float*)alloc((size_t)NNODES*4*4);
  float* veall  = (float*)alloc(72*9*4);
  int*   gb     = (int*)alloc((size_t)NEDGES*4);
  int*   csroff = (int*)alloc((size_t)(NNODES+1)*4);
  int*   csrsrc = (int*)alloc((size_t)NEA*4);
  int*   csreid = (int*)alloc((size_t)NEA*4);
  int*   goff   = (int*)alloc(NG*4);
  int*   gcur   = (int*)alloc(NG*4);
  int*   sortedeid = (int*)alloc((size_t)NEDGES*4);
  // ---- zero-initialized region (single memset) ----
  size_t z0 = woff;
  int*   deg    = (int*)alloc((size_t)NNODES*4);
  int*   cnt    = (int*)alloc((size_t)NNODES*4);
  int*   gcnt   = (int*)alloc(NG*4);
  float* og     = (float*)alloc((size_t)NG*OGW*4);
  float* pooled = (float*)alloc((size_t)NG*64*4);
  int*   cntg   = (int*)alloc((size_t)NG*4);
  size_t zlen = woff - z0;

  hipMemsetAsync(base + z0, 0, zlen, stream);

  // fused casts
  k_prep<<<ceil_div(800000+32768+262144+32768,256),256,0,stream>>>(x, xb, W1, Wt1, W2, Wt2, W3, Wt3);

  // CSR build + gb histogram (fused pass over edge_index)
  k_deg_gb<<<ceil_div(NEDGES,256),256,0,stream>>>(src, dst, batch, deg, gb, gcnt);
  k_scan  <<<1,1024,0,stream>>>(deg, csroff);
  k_fill  <<<ceil_div(NEDGES,256),256,0,stream>>>(src, dst, csroff, cnt, csrsrc, csreid);
  k_self  <<<ceil_div(NNODES,256),256,0,stream>>>(csroff, csrsrc, csreid);

  // 1-gram
  k_gscan   <<<1,NG,0,stream>>>(gcnt, goff, gcur);
  k_gscatter<<<ceil_div(NEDGES,256),256,0,stream>>>(gb, gcur, sortedeid);
  k_og2     <<<NG*16,256,0,stream>>>(eattr, goff, gcnt, sortedeid, og);

  // edge scores for all 3 layers
  k_ve_all    <<<1,704,0,stream>>>(We1, ae1, We2, ae2, We3, ae3, veall);
  k_se_all    <<<ceil_div(NEDGES,256),256,0,stream>>>(eattr, veall, se);
  k_seloop_all<<<ceil_div(NNODES,256),256,0,stream>>>(csroff, csreid, se, seloop);

  dim3 g128(4, ceil_div(NNODES,128));

  // ---- layer 1 ----
  k_gemm128<<<g128,256,0,stream>>>(xb, Wt1, xsb, NNODES, 64, as1, ad1, ssrc, sdst);
  k_agg12<<<NNODES,128,0,stream>>>(xsb, csroff, csrsrc, csreid, ssrc, sdst, se, seloop, 0, b1, hb);

  // ---- layer 2 ----
  k_gemm128<<<g128,256,0,stream>>>(hb, Wt2, xsb, NNODES, 512, as2, ad2, ssrc, sdst);
  k_agg12<<<NNODES,128,0,stream>>>(xsb, csroff, csrsrc, csreid, ssrc, sdst, se, seloop, 4, b2, hb);

  // ---- layer 3 ----
  k_gemm64<<<ceil_div(NNODES,64),256,0,stream>>>(hb, Wt3, xs3, NNODES);
  k_satt64<<<ceil_div(NNODES,4),256,0,stream>>>(xs3, as3, ad3, ssrc, sdst);
  k_agg3  <<<NNODES,64,0,stream>>>(xs3, csroff, csrsrc, csreid, ssrc, sdst, se, seloop, b3, h3);

  // ---- pool + FFN ----
  k_pool<<<ceil_div(NNODES,128),64,0,stream>>>(h3, batch, pooled, cntg);
  k_ffn <<<NG,192,0,stream>>>(pooled, cntg, og, Wf1, bf1, Wf2, bf2, out);
}